// Round 22
// baseline (186.569 us; speedup 1.0000x reference)
//
#include <hip/hip_runtime.h>
#include <hip/hip_bf16.h>

// Problem constants
#define BATCH 2
#define SEQ 512
#define DIM 768
#define HEADS 12
#define NEXP 8
#define FFDIM 3072
#define HDIM 64
#define NTOK (BATCH*SEQ)          // 1024
#define NENT (2*NTOK)             // 2048 (token, slot) entries
#define YPS ((long)NENT * DIM)    // partial-buffer stride

typedef __hip_bfloat16 bf16;
typedef __attribute__((ext_vector_type(8))) short s8v;
typedef __attribute__((ext_vector_type(4))) float f4v;

// ---- async global->LDS (16B per lane, wave-uniform LDS base + lane*16) ----
typedef __attribute__((address_space(1))) const unsigned char gas_u8;
typedef __attribute__((address_space(3))) unsigned char las_u8;
__device__ __forceinline__ void gload16(const void* g, void* l) {
    __builtin_amdgcn_global_load_lds((gas_u8*)g, (las_u8*)l, 16, 0, 0);
}

__device__ __forceinline__ float bfbits2f(unsigned hi16) {
    union { unsigned u; float f; } c; c.u = hi16; return c.f;
}
__device__ __forceinline__ unsigned short bf16bits(float f) {
    bf16 h = __float2bfloat16(f);
    return *reinterpret_cast<unsigned short*>(&h);
}

// ---------------- LayerNorm (LN1): one block per token ----------------
__global__ __launch_bounds__(256) void ln_kernel(const float* __restrict__ x,
                                                 const float* __restrict__ g,
                                                 const float* __restrict__ b,
                                                 bf16* __restrict__ outb) {
    int t = blockIdx.x;
    const float* xr = x + (long)t * DIM;
    int tid = threadIdx.x;
    float v0 = xr[tid], v1 = xr[tid + 256], v2 = xr[tid + 512];
    float s = v0 + v1 + v2;
    __shared__ float red[4];
    #pragma unroll
    for (int o = 32; o; o >>= 1) s += __shfl_xor(s, o);
    if ((tid & 63) == 0) red[tid >> 6] = s;
    __syncthreads();
    s = red[0] + red[1] + red[2] + red[3];
    float mu = s * (1.f / DIM);
    float d0 = v0 - mu, d1 = v1 - mu, d2 = v2 - mu;
    float q = d0*d0 + d1*d1 + d2*d2;
    __shared__ float red2[4];
    #pragma unroll
    for (int o = 32; o; o >>= 1) q += __shfl_xor(q, o);
    if ((tid & 63) == 0) red2[tid >> 6] = q;
    __syncthreads();
    q = red2[0] + red2[1] + red2[2] + red2[3];
    float rstd = rsqrtf(q * (1.f / DIM) + 1e-5f);
    bf16* ob = outb + (long)t * DIM;
    ob[tid]       = __float2bfloat16(d0 * rstd * g[tid]       + b[tid]);
    ob[tid + 256] = __float2bfloat16(d1 * rstd * g[tid + 256] + b[tid + 256]);
    ob[tid + 512] = __float2bfloat16(d2 * rstd * g[tid + 512] + b[tid + 512]);
}

// ---------------- LN2 fused with x1 assembly ----------------
__global__ __launch_bounds__(256) void ln2x1_kernel(const float* __restrict__ x,
                                                    const float* __restrict__ out_b,
                                                    const float* __restrict__ op,
                                                    const float* __restrict__ g,
                                                    const float* __restrict__ b,
                                                    float* __restrict__ x1,
                                                    float* __restrict__ t2,
                                                    bf16* __restrict__ t2b) {
    int t = blockIdx.x;
    long base = (long)t * DIM;
    int tid = threadIdx.x;
    const long TDl = (long)NTOK * DIM;
    float v[3];
    #pragma unroll
    for (int i = 0; i < 3; ++i) {
        long idx = base + tid + i * 256;
        v[i] = x[idx] + out_b[tid + i * 256] + op[idx] + op[idx + TDl];
        x1[idx] = v[i];
    }
    float s = v[0] + v[1] + v[2];
    __shared__ float red[4];
    #pragma unroll
    for (int o = 32; o; o >>= 1) s += __shfl_xor(s, o);
    if ((tid & 63) == 0) red[tid >> 6] = s;
    __syncthreads();
    s = red[0] + red[1] + red[2] + red[3];
    float mu = s * (1.f / DIM);
    float d[3];
    float q = 0.f;
    #pragma unroll
    for (int i = 0; i < 3; ++i) { d[i] = v[i] - mu; q += d[i] * d[i]; }
    __shared__ float red2[4];
    #pragma unroll
    for (int o = 32; o; o >>= 1) q += __shfl_xor(q, o);
    if ((tid & 63) == 0) red2[tid >> 6] = q;
    __syncthreads();
    q = red2[0] + red2[1] + red2[2] + red2[3];
    float rstd = rsqrtf(q * (1.f / DIM) + 1e-5f);
    #pragma unroll
    for (int i = 0; i < 3; ++i) {
        long idx = base + tid + i * 256;
        float o = d[i] * rstd * g[tid + i * 256] + b[tid + i * 256];
        t2[idx] = o;
        t2b[idx] = __float2bfloat16(o);
    }
}

// ---------------- MFMA GEMM device body (attention-side) ----------------
template<int WM, int WN, bool GROUPED, bool GELU, int OUTMODE>
__device__ __forceinline__ void dev_mfma_gemm(
    const bf16* __restrict__ A, const bf16* __restrict__ B,
    const float* __restrict__ bias, const float* __restrict__ resid,
    void* __restrict__ Cv,
    int M, int N, int K, int lda, int ldb, int ldc,
    int zdiv, int ksplit,
    long a_hi, long a_lo, long b_hi, long b_lo, long c_hi, long c_lo,
    long bias_stride, const int* __restrict__ grp_off, float alpha,
    int bx, int by, int bz, char* smem)
{
    constexpr int BM = 32 * WM, BN = 32 * WN;
    constexpr int ACH = BM * 4;     // 16B chunks in A tile
    constexpr int BCH = BN * 4;

    int z = bz;
    int ze = z / ksplit, ks = z % ksplit;
    int kper = K / ksplit;
    long aoff, boff, coff;
    int m_count = M;
    if (GROUPED) {
        int m0 = grp_off[ze], m1 = grp_off[ze + 1];
        m_count = m1 - m0;
        if (by * BM >= m_count) return;
        aoff = (long)m0 * lda;
        coff = (long)m0 * ldc;
        boff = (long)ze * b_hi;
    } else {
        int zh = ze / zdiv, zl = ze % zdiv;
        aoff = zh * a_hi + zl * a_lo;
        boff = zh * b_hi + zl * b_lo;
        coff = zh * c_hi + zl * c_lo;
    }
    const short* Ag = (const short*)(A + aoff);
    const short* Bg = (const short*)(B + boff);
    const float* biasp = bias ? bias + (long)ze * bias_stride : nullptr;
    float* Cf = (float*)Cv + coff;
    bf16*  Cb = (bf16*)Cv + coff;

    short* As = (short*)smem;
    short* Bs = As + BM * 32;

    int tid = threadIdx.x;
    int wv = tid >> 6, ln = tid & 63;
    int wr = wv >> 1, wc = wv & 1;
    int fr = ln & 15, fq = ln >> 4;
    int bm = by * BM, bn = bx * BN;

    f4v acc[WM][WN] = {};

    for (int k0 = ks * kper; k0 < (ks + 1) * kper; k0 += 32) {
        #pragma unroll
        for (int is = 0; is < ACH / 256; ++is) {
            int c = is * 256 + wv * 64 + ln;
            int m = c >> 2, kq = c & 3;
            int qg = kq ^ ((m >> 1) & 3);
            gload16(Ag + (long)(bm + m) * lda + k0 + qg * 8,
                    &As[(is * 256 + wv * 64) * 8]);
        }
        if constexpr (ACH % 256) {
            if (tid < ACH % 256) {
                int c = (ACH / 256) * 256 + tid;
                int m = c >> 2, kq = c & 3;
                int qg = kq ^ ((m >> 1) & 3);
                gload16(Ag + (long)(bm + m) * lda + k0 + qg * 8,
                        &As[((ACH / 256) * 256 + wv * 64) * 8]);
            }
        }
        #pragma unroll
        for (int is = 0; is < BCH / 256; ++is) {
            int c = is * 256 + wv * 64 + ln;
            int m = c >> 2, kq = c & 3;
            int qg = kq ^ ((m >> 1) & 3);
            gload16(Bg + (long)(bn + m) * ldb + k0 + qg * 8,
                    &Bs[(is * 256 + wv * 64) * 8]);
        }
        if constexpr (BCH % 256) {
            if (tid < BCH % 256) {
                int c = (BCH / 256) * 256 + tid;
                int m = c >> 2, kq = c & 3;
                int qg = kq ^ ((m >> 1) & 3);
                gload16(Bg + (long)(bn + m) * ldb + k0 + qg * 8,
                        &Bs[((BCH / 256) * 256 + wv * 64) * 8]);
            }
        }
        __syncthreads();
        s8v av[WM], bv[WN];
        #pragma unroll
        for (int i = 0; i < WM; ++i) {
            int row = wr * (WM * 16) + i * 16 + fr;
            av[i] = *(const s8v*)&As[row * 32 + (fq ^ ((row >> 1) & 3)) * 8];
        }
        #pragma unroll
        for (int j = 0; j < WN; ++j) {
            int row = wc * (WN * 16) + j * 16 + fr;
            bv[j] = *(const s8v*)&Bs[row * 32 + (fq ^ ((row >> 1) & 3)) * 8];
        }
        #pragma unroll
        for (int i = 0; i < WM; ++i)
            #pragma unroll
            for (int j = 0; j < WN; ++j)
                acc[i][j] = __builtin_amdgcn_mfma_f32_16x16x32_bf16(av[i], bv[j], acc[i][j], 0, 0, 0);
        __syncthreads();
    }

    #pragma unroll
    for (int i = 0; i < WM; ++i) {
        #pragma unroll
        for (int r = 0; r < 4; ++r) {
            int row = bm + wr * (WM * 16) + i * 16 + fq * 4 + r;
            if (GROUPED && row >= m_count) continue;
            #pragma unroll
            for (int j = 0; j < WN; ++j) {
                int col = bn + wc * (WN * 16) + j * 16 + fr;
                if (col < N) {
                    float v = acc[i][j][r] * alpha;
                    if (OUTMODE == 2) {
                        atomicAdd(&Cf[(long)row * ldc + col], v);
                    } else {
                        if (biasp) v += biasp[col];
                        if (GELU) v = 0.5f * v * (1.f + erff(v * 0.70710678118654752f));
                        if (resid) v += resid[(long)row * ldc + col];
                        if (OUTMODE == 1) Cb[(long)row * ldc + col] = __float2bfloat16(v);
                        else              Cf[(long)row * ldc + col] = v;
                    }
                }
            }
        }
    }
}

// Standalone wrapper (PV, out-proj)
template<int WM, int WN, bool GROUPED, bool GELU, int OUTMODE>
__global__ __launch_bounds__(256) void mfma_gemm(
    const bf16* A, const bf16* B, const float* bias, const float* resid,
    void* Cv, int M, int N, int K, int lda, int ldb, int ldc,
    int zdiv, int ksplit,
    long a_hi, long a_lo, long b_hi, long b_lo, long c_hi, long c_lo,
    long bias_stride, const int* grp_off, float alpha)
{
    __shared__ char smem[(32 * WM + 32 * WN) * 32 * 2];
    dev_mfma_gemm<WM, WN, GROUPED, GELU, OUTMODE>(
        A, B, bias, resid, Cv, M, N, K, lda, ldb, ldc, zdiv, ksplit,
        a_hi, a_lo, b_hi, b_lo, c_hi, c_lo, bias_stride, grp_off, alpha,
        blockIdx.x, blockIdx.y, blockIdx.z, smem);
}

// ---------------- weight transpose-convert tile (blocked output) -------------
// id<4608: w1 (K=768, C=3072); else w2 (K=3072, C=768).
// Output bf16 chunk-blocked [K/8][C][8]. Needs 64*65*4 = 16640B of smem.
__device__ __forceinline__ void dev_wtrans(int id,
                                           const float* __restrict__ w1,
                                           bf16* __restrict__ w1t,
                                           const float* __restrict__ w2,
                                           bf16* __restrict__ w2t,
                                           char* smem) {
    const float* in; bf16* out; int C, e, ct, rt;
    if (id < 4608) {                     // w1: 8 x (48 ct x 12 rt)
        e = id / 576; int rem = id % 576; ct = rem / 12; rt = rem % 12;
        in = w1; out = w1t; C = FFDIM;
    } else {
        id -= 4608;                      // w2: 8 x (12 ct x 48 rt)
        e = id / 576; int rem = id % 576; ct = rem / 48; rt = rem % 48;
        in = w2; out = w2t; C = DIM;
    }
    long ibase = (long)e * DIM * FFDIM;
    int rt0 = rt * 64, ct0 = ct * 64;
    float (*tile)[65] = (float(*)[65])smem;
    int t = threadIdx.x;
    {
        int q = t >> 4, cq = t & 15;
        #pragma unroll
        for (int i = 0; i < 4; ++i) {
            int row = q + i * 16;
            float4 v = *(const float4*)&in[ibase + (long)(rt0 + row) * C + ct0 + cq * 4];
            tile[row][cq * 4]     = v.x;
            tile[row][cq * 4 + 1] = v.y;
            tile[row][cq * 4 + 2] = v.z;
            tile[row][cq * 4 + 3] = v.w;
        }
    }
    __syncthreads();
    {
        int kb2 = t >> 6, n = t & 63;
        #pragma unroll
        for (int i = 0; i < 2; ++i) {
            int kblk = kb2 + 4 * i;
            unsigned w[4];
            #pragma unroll
            for (int j = 0; j < 4; ++j) {
                w[j] = ((unsigned)bf16bits(tile[kblk * 8 + 2 * j + 1][n]) << 16)
                     | bf16bits(tile[kblk * 8 + 2 * j][n]);
            }
            uint4 u; u.x = w[0]; u.y = w[1]; u.z = w[2]; u.w = w[3];
            *(uint4*)&out[ibase + ((long)(rt0 >> 3) + kblk) * C * 8 + (long)(ct0 + n) * 8] = u;
        }
    }
}

// ---------------- fused: qkv GEMM + w1 transpose (INTERLEAVED block map) ------
// 5184 blocks = 576 GEMM + 4608 transpose, ratio 9: bid%9==0 -> GEMM bid/9,
// else transpose bid - bid/9 - 1. Interleaving keeps both block types
// co-resident across the kernel lifetime (overlap, not serial phases).
__global__ __launch_bounds__(256) void qkv_w1_kernel(
    const bf16* __restrict__ h_b, const bf16* __restrict__ in_wb,
    const float* __restrict__ in_b, bf16* __restrict__ qkv_b,
    const float* __restrict__ w1, bf16* __restrict__ w1t,
    const float* __restrict__ w2, bf16* __restrict__ w2t) {
    __shared__ char smem[16640];
    int bid = blockIdx.x;
    if (bid % 9 == 0) {
        int g = bid / 9;                               // 0..575
        dev_mfma_gemm<2, 2, false, false, 1>(
            h_b, in_wb, in_b, nullptr, qkv_b,
            NTOK, 3 * DIM, DIM, DIM, DIM, 3 * DIM,
            1, 1, 0, 0, 0, 0, 0, 0, 0, nullptr, 1.f,
            g % 36, g / 36, 0, smem);
    } else {
        int tr = bid - bid / 9 - 1;                    // 0..4607 = w1 ids
        dev_wtrans(tr, w1, w1t, w2, w2t, smem);
    }
}

// ---------------- fused: scores GEMM + w2 transpose (INTERLEAVED) -------------
// 5376 blocks = 768 GEMM + 4608 transpose, ratio 7.
__global__ __launch_bounds__(256) void scores_w2_kernel(
    const bf16* __restrict__ qkv_b, bf16* __restrict__ scores,
    const float* __restrict__ w1, bf16* __restrict__ w1t,
    const float* __restrict__ w2, bf16* __restrict__ w2t) {
    __shared__ char smem[16640];
    int bid = blockIdx.x;
    if (bid % 7 == 0) {
        int g = bid / 7;                               // 0..767
        dev_mfma_gemm<2, 4, false, false, 1>(
            qkv_b, qkv_b + DIM, nullptr, nullptr, scores,
            SEQ, SEQ, HDIM, 3 * DIM, 3 * DIM, SEQ,
            HEADS, 1, (long)SEQ * 3 * DIM, HDIM, (long)SEQ * 3 * DIM, HDIM,
            (long)HEADS * SEQ * SEQ, (long)SEQ * SEQ,
            0, nullptr, 0.125f,
            g % 4, (g >> 2) & 7, g >> 5, smem);
    } else {
        int tr = bid - bid / 7 - 1;                    // 0..4607 -> w2 ids
        dev_wtrans(4608 + tr, w1, w1t, w2, w2t, smem);
    }
}

// ---------------- MoE grouped GEMM v12: chunk-blocked B layout ----------------
template<int FM, int FN, int XT, int YCAP, int KS, bool GELU, int OUTMODE, bool GATHER>
__global__ __launch_bounds__(256) void moe_gemm(
    const bf16* __restrict__ A, const bf16* __restrict__ B,
    const float* __restrict__ bias, void* __restrict__ Cv,
    int lda, int Nt, int ldc, int Ktot, long b_hi, long bias_stride,
    const int* __restrict__ grp_off, const int* __restrict__ entry_tok,
    int N, long pstride)
{
    static_assert(OUTMODE != 1 || KS == 1, "plain bf16 store requires no split-K");
    constexpr int BM = FM * 32, BN = FN * 32;
    constexpr int GA = BM / 64;
    constexpr int GB = BN / 64;
    constexpr int G = GA + GB;

    int bid = blockIdx.x;
    int e = bid & 7;
    int r = bid >> 3;
    int xt = r % XT; r /= XT;
    int yt = r % YCAP;
    int ks = r / YCAP;
    int m0 = grp_off[e], m1 = grp_off[e + 1];
    int m_count = m1 - m0;
    int bm = yt * BM;
    if (bm >= m_count) return;
    int bn = xt * BN;
    int kper = Ktot / KS;

    const short* Ag = (const short*)A + (GATHER ? 0 : (long)m0 * lda);
    const short* Bg = (const short*)(B + (long)e * b_hi);
    const float* biasp = bias ? bias + (long)e * bias_stride : nullptr;
    float* Cf = (float*)Cv + (long)m0 * ldc + (long)ks * pstride;
    bf16*  Cb = (bf16*)Cv + (long)m0 * ldc;

    __shared__ short As[3][BM * 32];
    __shared__ short Bs[3][BN * 32];

    int tid = threadIdx.x;
    int wv = tid >> 6, ln = tid & 63;
    int wr = wv >> 1, wc = wv & 1;
    int fr = ln & 15, fq = ln >> 4;

    long arow[GA];
    #pragma unroll
    for (int is = 0; is < GA; ++is) {
        int c = is * 256 + wv * 64 + ln;
        int m = c >> 2;
        if (GATHER) {
            int gi = m0 + bm + m;
            arow[is] = (long)entry_tok[gi < NENT ? gi : NENT - 1] * lda;
        } else {
            arow[is] = (long)(bm + m) * lda;
        }
    }

    f4v acc[FM][FN] = {};

    auto stage = [&](int buf, int k0) {
        #pragma unroll
        for (int is = 0; is < GA; ++is) {
            int c = is * 256 + wv * 64 + ln;
            int m = c >> 2, q = c & 3;
            int qg = q ^ ((m >> 1) & 3);
            gload16(Ag + arow[is] + k0 + qg * 8,
                    &As[buf][(is * 256 + wv * 64) * 8]);
        }
        #pragma unroll
        for (int is = 0; is < GB; ++is) {
            int c = is * 256 + wv * 64 + ln;
            int n = c >> 2, q = c & 3;
            int qg = q ^ ((n >> 1) & 3);
            gload16(Bg + ((long)(k0 >> 3) + qg) * Nt * 8 + (long)(bn + n) * 8,
                    &Bs[buf][(is * 256 + wv * 64) * 8]);
        }
    };

    int kbeg = ks * kper;
    int nit = kper / 32;
    stage(0, kbeg);
    if (nit > 1) stage(1, kbeg + 32);

    for (int it = 0; it < nit; ++it) {
        if (it + 1 < nit) asm volatile("s_waitcnt vmcnt(%0)" :: "i"(G) : "memory");
        else              asm volatile("s_waitcnt vmcnt(0)" ::: "memory");
        __builtin_amdgcn_s_barrier();
        if (it + 2 < nit) stage((it + 2) % 3, kbeg + (it + 2) * 32);
        int cur = it % 3;
        __builtin_amdgcn_s_setprio(1);
        {
            s8v av[FM], bv[FN];
            #pragma unroll
            for (int i = 0; i < FM; ++i) {
                int row = wr * (FM * 16) + i * 16 + fr;
                av[i] = *(const s8v*)&As[cur][row * 32 + (fq ^ ((row >> 1) & 3)) * 8];
            }
            #pragma unroll
            for (int j = 0; j < FN; ++j) {
                int row = wc * (FN * 16) + j * 16 + fr;
                bv[j] = *(const s8v*)&Bs[cur][row * 32 + (fq ^ ((row >> 1) & 3)) * 8];
            }
            #pragma unroll
            for (int i = 0; i < FM; ++i)
                #pragma unroll
                for (int j = 0; j < FN; ++j)
                    acc[i][j] = __builtin_amdgcn_mfma_f32_16x16x32_bf16(av[i], bv[j], acc[i][j], 0, 0, 0);
        }
        __builtin_amdgcn_s_setprio(0);
    }

    #pragma unroll
    for (int i = 0; i < FM; ++i) {
        #pragma unroll
        for (int rr = 0; rr < 4; ++rr) {
            int row = bm + wr * (FM * 16) + i * 16 + fq * 4 + rr;
            if (row >= m_count) continue;
            #pragma unroll
            for (int j = 0; j < FN; ++j) {
                int col = bn + wc * (FN * 16) + j * 16 + fr;
                float v = acc[i][j][rr];
                if (OUTMODE == 0) {
                    Cf[(long)row * ldc + col] = v;
                } else {
                    if (biasp) v += biasp[col];
                    if (GELU) v = 0.5f * v * (1.f + erff(v * 0.70710678118654752f));
                    Cb[(long)row * ldc + col] = __float2bfloat16(v);
                }
            }
        }
    }
}

// ---------------- softmax over 512, bf16 in -> bf16 out, wave per row --------
__global__ __launch_bounds__(256) void softmax512b(const bf16* __restrict__ s,
                                                   bf16* __restrict__ attn) {
    long row = (long)blockIdx.x * 4 + (threadIdx.x >> 6);
    int ln = threadIdx.x & 63;
    const unsigned* p = (const unsigned*)(s + row * 512);
    uint4 v = *(const uint4*)(p + ln * 4);
    unsigned u[4] = {v.x, v.y, v.z, v.w};
    float f[8];
    #pragma unroll
    for (int j = 0; j < 4; ++j) {
        f[2*j]   = bfbits2f(u[j] << 16);
        f[2*j+1] = bfbits2f(u[j] & 0xffff0000u);
    }
    float m = f[0];
    #pragma unroll
    for (int j = 1; j < 8; ++j) m = fmaxf(m, f[j]);
    #pragma unroll
    for (int o = 32; o; o >>= 1) m = fmaxf(m, __shfl_xor(m, o));
    float e[8], ssum = 0.f;
    #pragma unroll
    for (int j = 0; j < 8; ++j) { e[j] = expf(f[j] - m); ssum += e[j]; }
    #pragma unroll
    for (int o = 32; o; o >>= 1) ssum += __shfl_xor(ssum, o);
    float inv = 1.f / ssum;
    unsigned w[4];
    #pragma unroll
    for (int j = 0; j < 4; ++j) {
        bf16 lo = __float2bfloat16(e[2*j] * inv);
        bf16 hi = __float2bfloat16(e[2*j+1] * inv);
        w[j] = ((unsigned)*(unsigned short*)&hi << 16) | *(unsigned short*)&lo;
    }
    uint4 o4; o4.x = w[0]; o4.y = w[1]; o4.z = w[2]; o4.w = w[3];
    *(uint4*)((unsigned*)(attn + row * 512) + ln * 4) = o4;
}

// ---------------- V transpose: qkv bf16 [tok][2304] -> vt [z][64][512] ------
__global__ __launch_bounds__(256) void vt_kernel(const bf16* __restrict__ qkvb,
                                                 bf16* __restrict__ vt) {
    int st = blockIdx.x;
    int z = blockIdx.y;
    int b = z / HEADS, h = z % HEADS;
    __shared__ short tile[64][65];
    int t = threadIdx.x;
    int d = t & 63, s0 = t >> 6;
    const short* q = (const short*)qkvb;
    #pragma unroll
    for (int i = 0; i < 16; ++i) {
        int s = st * 64 + s0 + i * 4;
        tile[s0 + i * 4][d] = q[(long)(b * SEQ + s) * 2304 + 2 * DIM + h * HDIM + d];
    }
    __syncthreads();
    short* o = (short*)vt;
    #pragma unroll
    for (int i = 0; i < 16; ++i) {
        int d2 = (t >> 6) + i * 4;
        o[(long)(z * 64 + d2) * 512 + st * 64 + (t & 63)] = tile[t & 63][d2];
    }
}

// ---------------- dual f32 -> bf16 convert (merged launches) ----------------
__global__ __launch_bounds__(256) void cvt2_kernel(const float* __restrict__ a, long na,
                                                   const float* __restrict__ b, long nb,
                                                   bf16* __restrict__ oa,
                                                   bf16* __restrict__ ob) {
    long i = ((long)blockIdx.x * 256 + threadIdx.x) * 4;
    const float* src; bf16* dst; long idx;
    if (i < na) { src = a; dst = oa; idx = i; }
    else if (i < na + nb) { src = b; dst = ob; idx = i - na; }
    else return;
    float4 v = *(const float4*)(src + idx);
    dst[idx]     = __float2bfloat16(v.x);
    dst[idx + 1] = __float2bfloat16(v.y);
    dst[idx + 2] = __float2bfloat16(v.z);
    dst[idx + 3] = __float2bfloat16(v.w);
}

// ---------------- router: logits, softmax, top2, renorm ----------------
__global__ __launch_bounds__(64) void router_kernel(const float* __restrict__ t2,
                                                    const float* __restrict__ rw,
                                                    const float* __restrict__ rb,
                                                    int* __restrict__ e_sel,
                                                    float* __restrict__ w_sel) {
    int t = blockIdx.x;
    int lane = threadIdx.x;
    const float* tr = t2 + (long)t * DIM;
    float tv[12];
    #pragma unroll
    for (int i = 0; i < 12; ++i) tv[i] = tr[lane + 64 * i];
    float logits[NEXP];
    #pragma unroll
    for (int e = 0; e < NEXP; ++e) {
        const float* wr = rw + (long)e * DIM;
        float s = 0.f;
        #pragma unroll
        for (int i = 0; i < 12; ++i) s += tv[i] * wr[lane + 64 * i];
        #pragma unroll
        for (int o = 32; o; o >>= 1) s += __shfl_xor(s, o);
        logits[e] = s + rb[e];
    }
    if (lane == 0) {
        int e0 = -1, e1 = -1;
        float l0 = -1e30f, l1 = -1e30f;
        #pragma unroll
        for (int e = 0; e < NEXP; ++e) {
            float l = logits[e];
            if (l > l0) { l1 = l0; e1 = e0; l0 = l; e0 = e; }
            else if (l > l1) { l1 = l; e1 = e; }
        }
        float p1 = expf(l1 - l0);
        float inv = 1.f / (1.f + p1);
        e_sel[t * 2] = e0;  e_sel[t * 2 + 1] = e1;
        w_sel[t * 2] = inv; w_sel[t * 2 + 1] = p1 * inv;
    }
}

// ---------------- build per-expert entry lists (single block) ----------------
__global__ __launch_bounds__(1024) void build_lists(const int* __restrict__ e_sel,
                                                    int* __restrict__ entry_tok,
                                                    int* __restrict__ pos,
                                                    int* __restrict__ grp_off) {
    __shared__ int cnt[NEXP];
    __shared__ int off[NEXP + 1];
    __shared__ int cur[NEXP];
    int tid = threadIdx.x;
    if (tid < NEXP) cnt[tid] = 0;
    __syncthreads();
    for (int i = tid; i < NENT; i += 1024) atomicAdd(&cnt[e_sel[i]], 1);
    __syncthreads();
    if (tid == 0) {
        off[0] = 0;
        for (int e = 0; e < NEXP; ++e) off[e + 1] = off[e] + cnt[e];
        for (int e = 0; e < NEXP; ++e) cur[e] = off[e];
    }
    __syncthreads();
    for (int i = tid; i < NENT; i += 1024) {
        int e = e_sel[i];
        int p = atomicAdd(&cur[e], 1);
        entry_tok[p] = i >> 1;
        pos[i] = p;
    }
    if (tid < NEXP + 1) grp_off[tid] = off[tid];
}

// ---------------- final combine (float4): out = x1 + sum_s w_s*(b2+sum parts) -
__global__ __launch_bounds__(256) void combine_kernel(const float* __restrict__ x1,
                                                      const float* __restrict__ ypart,
                                                      const float* __restrict__ b2,
                                                      const int* __restrict__ pos,
                                                      const int* __restrict__ e_sel,
                                                      const float* __restrict__ wsel,
                                                      float* __restrict__ out) {
    long i4 = (long)blockIdx.x * 256 + threadIdx.x;      // float4 units; 196608 total
    if (i4 >= (long)NTOK * DIM / 4) return;
    int t = (int)(i4 / 192), d4 = (int)(i4 % 192);
    const float4* x1v = (const float4*)x1;
    const float4* ypv = (const float4*)ypart;
    const float4* b2v = (const float4*)b2;
    float4 v = x1v[i4];
    #pragma unroll
    for (int s = 0; s < 2; ++s) {
        long base = (long)pos[t * 2 + s] * 192 + d4;
        float4 y = b2v[(long)e_sel[t * 2 + s] * 192 + d4];
        #pragma unroll
        for (int ks = 0; ks < 4; ++ks) {
            float4 pp = ypv[base + ks * (YPS / 4)];
            y.x += pp.x; y.y += pp.y; y.z += pp.z; y.w += pp.w;
        }
        float w = wsel[t * 2 + s];
        v.x += w * y.x; v.y += w * y.y; v.z += w * y.z; v.w += w * y.w;
    }
    ((float4*)out)[i4] = v;
}

extern "C" void kernel_launch(void* const* d_in, const int* in_sizes, int n_in,
                              void* d_out, int out_size, void* d_ws, size_t ws_size,
                              hipStream_t stream) {
    const float* x        = (const float*)d_in[0];
    const float* ln1_g    = (const float*)d_in[1];
    const float* ln1_b    = (const float*)d_in[2];
    const float* ln2_g    = (const float*)d_in[3];
    const float* ln2_b    = (const float*)d_in[4];
    const float* in_w     = (const float*)d_in[5];
    const float* in_b     = (const float*)d_in[6];
    const float* out_w    = (const float*)d_in[7];
    const float* out_b    = (const float*)d_in[8];
    const float* router_w = (const float*)d_in[9];
    const float* router_b = (const float*)d_in[10];
    const float* w1       = (const float*)d_in[11];
    const float* b1       = (const float*)d_in[12];
    const float* w2       = (const float*)d_in[13];
    const float* b2       = (const float*)d_in[14];
    float* out = (float*)d_out;

    const long TD = (long)NTOK * DIM;
    char* p = (char*)d_ws;
    size_t off = 0;
    auto alloc = [&](size_t bytes) -> void* {
        void* r = p + off; off += (bytes + 255) & ~(size_t)255; return r;
    };
    bf16*  h_b    = (bf16*)alloc(TD * 2);
    bf16*  in_wb  = (bf16*)alloc(2304L * 768 * 2);
    bf16*  qkv_b  = (bf16*)alloc(1024L * 2304 * 2);
    bf16*  out_wb = (bf16*)alloc(768L * 768 * 2);
    bf16*  vt_b   = (bf16*)alloc((24L * 64 + 64) * 512 * 2);
    bf16*  oat_b  = (bf16*)alloc(TD * 2);
    float* opart  = (float*)alloc(2 * TD * 4);                 // out-proj K-partials
    float* x1     = (float*)alloc(TD * 4);
    float* t2     = (float*)alloc(TD * 4);
    bf16*  t2b    = (bf16*)alloc((NTOK + 256L) * DIM * 2);     // +pad (BM overread)
    bf16*  w1t    = (bf16*)alloc(8L * 3072 * 768 * 2);         // NOT aliased (fused xpose)
    bf16*  w2t    = (bf16*)alloc(8L * 768 * 3072 * 2);
    bf16*  scores = (bf16*)alloc(24L * 512 * 512 * 2);
    bf16*  attn   = (bf16*)alloc(24L * 512 * 512 * 2);
    bf16*  hid    = (bf16*)alloc((2048L + 256) * 3072 * 2);    // +pad
    float* ypart  = (float*)alloc(4 * YPS * 4);                // 4 split-K partials
    int*   e_sel     = (int*)alloc(NENT * 4);
    float* w_sel     = (float*)alloc(NENT * 4);
    int*   entry_tok = (int*)alloc(NENT * 4);
    int*   pos       = (int*)alloc(NENT * 4);
    int*   grp_off   = (int*)alloc(64);

    // 1. LN1 -> h bf16
    ln_kernel<<<NTOK, 256, 0, stream>>>(x, ln1_g, ln1_b, h_b);
    // 2. attention weight converts (merged; already [N][K])
    cvt2_kernel<<<2304, 256, 0, stream>>>(in_w, 2304L * 768, out_w, 768L * 768,
                                          in_wb, out_wb);
    // 3. FUSED+INTERLEAVED: qkv GEMM (576) + w1 transpose (4608)
    qkv_w1_kernel<<<576 + 4608, 256, 0, stream>>>(h_b, in_wb, in_b, qkv_b,
                                                  w1, w1t, w2, w2t);
    // 4. FUSED+INTERLEAVED: scores GEMM (768) + w2 transpose (4608)
    scores_w2_kernel<<<768 + 4608, 256, 0, stream>>>(qkv_b, scores,
                                                     w1, w1t, w2, w2t);
    // 5. softmax (wave per row) -> attn bf16
    softmax512b<<<24 * SEQ / 4, 256, 0, stream>>>(scores, attn);
    // 6. V transpose
    vt_kernel<<<dim3(8, 24), 256, 0, stream>>>(qkv_b, vt_b);
    // 7. o = attn @ V -> oat bf16   BM=32: 384 blocks
    mfma_gemm<1, 2, false, false, 1><<<dim3(1, 16, 24), 256, 0, stream>>>(
        attn, vt_b, nullptr, nullptr, oat_b,
        SEQ, HDIM, SEQ, SEQ, SEQ, DIM,
        HEADS, 1, (long)HEADS * SEQ * SEQ, (long)SEQ * SEQ,
        (long)HEADS * HDIM * SEQ, (long)HDIM * SEQ,
        (long)SEQ * DIM, HDIM,
        0, nullptr, 1.f);
    // 8. out-proj split-K x2, plain partial stores
    mfma_gemm<2, 2, false, false, 0><<<dim3(12, 16, 2), 256, 0, stream>>>(
        oat_b, out_wb, nullptr, nullptr, opart,
        NTOK, DIM, 384, DIM, DIM, DIM,
        2, 1, 0, 384, 0, 384, 0, TD, 0, nullptr, 1.f);
    // 9. LN2 fused with x1 assembly
    ln2x1_kernel<<<NTOK, 256, 0, stream>>>(x, out_b, opart, ln2_g, ln2_b,
                                           x1, t2, t2b);
    // 10. router
    router_kernel<<<NTOK, 64, 0, stream>>>(t2, router_w, router_b, e_sel, w_sel);
    // 11. build lists
    build_lists<<<1, 1024, 0, stream>>>(e_sel, entry_tok, pos, grp_off);
    // 12. FFN1 grouped, GATHER-fused A: hid = gelu(t2b[tok] @ w1 + b1) -> bf16
    moe_gemm<4, 4, 24, 8, 1, true, 1, true><<<8 * 24 * 8, 256, 0, stream>>>(
        t2b, w1t, b1, hid,
        DIM, FFDIM, FFDIM, DIM, (long)FFDIM * DIM, FFDIM, grp_off, entry_tok,
        FFDIM, 0);
    // 13. FFN2 grouped split-K x4, plain partial stores
    moe_gemm<4, 4, 6, 8, 4, false, 0, false><<<8 * 6 * 8 * 4, 256, 0, stream>>>(
        hid, w2t, nullptr, ypart,
        FFDIM, DIM, DIM, FFDIM, (long)FFDIM * DIM, 0, grp_off, nullptr,
        DIM, YPS);
    // 14. combine (float4)
    combine_kernel<<<768, 256, 0, stream>>>(x1, ypart, b2, pos, e_sel, w_sel, out);
}

// Round 23
// 179.957 us; speedup vs baseline: 1.0367x; 1.0367x over previous
//
#include <hip/hip_runtime.h>
#include <hip/hip_bf16.h>

// Problem constants
#define BATCH 2
#define SEQ 512
#define DIM 768
#define HEADS 12
#define NEXP 8
#define FFDIM 3072
#define HDIM 64
#define NTOK (BATCH*SEQ)          // 1024
#define NENT (2*NTOK)             // 2048 (token, slot) entries
#define YPS ((long)NENT * DIM)    // partial-buffer stride

typedef __hip_bfloat16 bf16;
typedef __attribute__((ext_vector_type(8))) short s8v;
typedef __attribute__((ext_vector_type(4))) float f4v;

// ---- async global->LDS (16B per lane, wave-uniform LDS base + lane*16) ----
typedef __attribute__((address_space(1))) const unsigned char gas_u8;
typedef __attribute__((address_space(3))) unsigned char las_u8;
__device__ __forceinline__ void gload16(const void* g, void* l) {
    __builtin_amdgcn_global_load_lds((gas_u8*)g, (las_u8*)l, 16, 0, 0);
}

__device__ __forceinline__ float bfbits2f(unsigned hi16) {
    union { unsigned u; float f; } c; c.u = hi16; return c.f;
}
__device__ __forceinline__ unsigned short bf16bits(float f) {
    bf16 h = __float2bfloat16(f);
    return *reinterpret_cast<unsigned short*>(&h);
}
__device__ __forceinline__ uint2 pack4bf(float a, float b, float c, float d) {
    uint2 u;
    u.x = ((unsigned)bf16bits(b) << 16) | bf16bits(a);
    u.y = ((unsigned)bf16bits(d) << 16) | bf16bits(c);
    return u;
}

// ---------------- LN1 (vectorized) + weight cvt, fused ----------------
// blocks 0..1023: LN1 over x -> h_b (bf16). blocks 1024..3327: cvt in_w/out_w.
__global__ __launch_bounds__(256) void ln1_cvt_kernel(
    const float* __restrict__ x, const float* __restrict__ g,
    const float* __restrict__ b, bf16* __restrict__ outb,
    const float* __restrict__ wa, long na, const float* __restrict__ wb, long nb,
    bf16* __restrict__ oa, bf16* __restrict__ ob2) {
    int bid = blockIdx.x;
    int tid = threadIdx.x;
    if (bid >= NTOK) {                   // cvt part
        long i = ((long)(bid - NTOK) * 256 + tid) * 4;
        const float* src; bf16* dst; long idx;
        if (i < na) { src = wa; dst = oa; idx = i; }
        else if (i < na + nb) { src = wb; dst = ob2; idx = i - na; }
        else return;
        float4 v = *(const float4*)(src + idx);
        *(uint2*)(dst + idx) = pack4bf(v.x, v.y, v.z, v.w);
        return;
    }
    // LN1, float4 path: 192 active lanes
    long base4 = (long)bid * 192;
    float4 v = {0.f, 0.f, 0.f, 0.f};
    if (tid < 192) v = ((const float4*)x)[base4 + tid];
    float s = v.x + v.y + v.z + v.w;
    __shared__ float red[4];
    #pragma unroll
    for (int o = 32; o; o >>= 1) s += __shfl_xor(s, o);
    if ((tid & 63) == 0) red[tid >> 6] = s;
    __syncthreads();
    s = red[0] + red[1] + red[2] + red[3];
    float mu = s * (1.f / DIM);
    float4 d = {v.x - mu, v.y - mu, v.z - mu, v.w - mu};
    float q = (tid < 192) ? (d.x*d.x + d.y*d.y + d.z*d.z + d.w*d.w) : 0.f;
    __shared__ float red2[4];
    #pragma unroll
    for (int o = 32; o; o >>= 1) q += __shfl_xor(q, o);
    if ((tid & 63) == 0) red2[tid >> 6] = q;
    __syncthreads();
    q = red2[0] + red2[1] + red2[2] + red2[3];
    float rstd = rsqrtf(q * (1.f / DIM) + 1e-5f);
    if (tid < 192) {
        float4 g4 = ((const float4*)g)[tid];
        float4 b4 = ((const float4*)b)[tid];
        ((uint2*)outb)[base4 + tid] = pack4bf(
            d.x * rstd * g4.x + b4.x, d.y * rstd * g4.y + b4.y,
            d.z * rstd * g4.z + b4.z, d.w * rstd * g4.w + b4.w);
    }
}

// ---------------- LN2 fused with x1 assembly (vectorized) ----------------
// x1 = x + out_b + opart0 + opart1 ; t2/t2b = LN(x1)
__global__ __launch_bounds__(256) void ln2x1_kernel(const float* __restrict__ x,
                                                    const float* __restrict__ out_b,
                                                    const float* __restrict__ op,
                                                    const float* __restrict__ g,
                                                    const float* __restrict__ b,
                                                    float* __restrict__ x1,
                                                    float* __restrict__ t2,
                                                    bf16* __restrict__ t2b) {
    int t = blockIdx.x;
    int tid = threadIdx.x;
    const long TD4 = (long)NTOK * DIM / 4;
    long base4 = (long)t * 192;
    float4 v = {0.f, 0.f, 0.f, 0.f};
    if (tid < 192) {
        long i4 = base4 + tid;
        float4 xv = ((const float4*)x)[i4];
        float4 ob = ((const float4*)out_b)[tid];
        float4 o0 = ((const float4*)op)[i4];
        float4 o1 = ((const float4*)op)[i4 + TD4];
        v.x = xv.x + ob.x + o0.x + o1.x;
        v.y = xv.y + ob.y + o0.y + o1.y;
        v.z = xv.z + ob.z + o0.z + o1.z;
        v.w = xv.w + ob.w + o0.w + o1.w;
        ((float4*)x1)[i4] = v;
    }
    float s = v.x + v.y + v.z + v.w;
    __shared__ float red[4];
    #pragma unroll
    for (int o = 32; o; o >>= 1) s += __shfl_xor(s, o);
    if ((tid & 63) == 0) red[tid >> 6] = s;
    __syncthreads();
    s = red[0] + red[1] + red[2] + red[3];
    float mu = s * (1.f / DIM);
    float4 d = {v.x - mu, v.y - mu, v.z - mu, v.w - mu};
    float q = (tid < 192) ? (d.x*d.x + d.y*d.y + d.z*d.z + d.w*d.w) : 0.f;
    __shared__ float red2[4];
    #pragma unroll
    for (int o = 32; o; o >>= 1) q += __shfl_xor(q, o);
    if ((tid & 63) == 0) red2[tid >> 6] = q;
    __syncthreads();
    q = red2[0] + red2[1] + red2[2] + red2[3];
    float rstd = rsqrtf(q * (1.f / DIM) + 1e-5f);
    if (tid < 192) {
        long i4 = base4 + tid;
        float4 g4 = ((const float4*)g)[tid];
        float4 b4 = ((const float4*)b)[tid];
        float o0 = d.x * rstd * g4.x + b4.x;
        float o1 = d.y * rstd * g4.y + b4.y;
        float o2 = d.z * rstd * g4.z + b4.z;
        float o3 = d.w * rstd * g4.w + b4.w;
        float4 ov = {o0, o1, o2, o3};
        ((float4*)t2)[i4] = ov;
        ((uint2*)t2b)[i4] = pack4bf(o0, o1, o2, o3);
    }
}

// ---------------- MFMA GEMM device body (attention-side) ----------------
template<int WM, int WN, bool GROUPED, bool GELU, int OUTMODE>
__device__ __forceinline__ void dev_mfma_gemm(
    const bf16* __restrict__ A, const bf16* __restrict__ B,
    const float* __restrict__ bias, const float* __restrict__ resid,
    void* __restrict__ Cv,
    int M, int N, int K, int lda, int ldb, int ldc,
    int zdiv, int ksplit,
    long a_hi, long a_lo, long b_hi, long b_lo, long c_hi, long c_lo,
    long bias_stride, const int* __restrict__ grp_off, float alpha,
    int bx, int by, int bz, char* smem)
{
    constexpr int BM = 32 * WM, BN = 32 * WN;
    constexpr int ACH = BM * 4;     // 16B chunks in A tile
    constexpr int BCH = BN * 4;

    int z = bz;
    int ze = z / ksplit, ks = z % ksplit;
    int kper = K / ksplit;
    long aoff, boff, coff;
    int m_count = M;
    if (GROUPED) {
        int m0 = grp_off[ze], m1 = grp_off[ze + 1];
        m_count = m1 - m0;
        if (by * BM >= m_count) return;
        aoff = (long)m0 * lda;
        coff = (long)m0 * ldc;
        boff = (long)ze * b_hi;
    } else {
        int zh = ze / zdiv, zl = ze % zdiv;
        aoff = zh * a_hi + zl * a_lo;
        boff = zh * b_hi + zl * b_lo;
        coff = zh * c_hi + zl * c_lo;
    }
    const short* Ag = (const short*)(A + aoff);
    const short* Bg = (const short*)(B + boff);
    const float* biasp = bias ? bias + (long)ze * bias_stride : nullptr;
    float* Cf = (float*)Cv + coff;
    bf16*  Cb = (bf16*)Cv + coff;

    short* As = (short*)smem;
    short* Bs = As + BM * 32;

    int tid = threadIdx.x;
    int wv = tid >> 6, ln = tid & 63;
    int wr = wv >> 1, wc = wv & 1;
    int fr = ln & 15, fq = ln >> 4;
    int bm = by * BM, bn = bx * BN;

    f4v acc[WM][WN] = {};

    for (int k0 = ks * kper; k0 < (ks + 1) * kper; k0 += 32) {
        #pragma unroll
        for (int is = 0; is < ACH / 256; ++is) {
            int c = is * 256 + wv * 64 + ln;
            int m = c >> 2, kq = c & 3;
            int qg = kq ^ ((m >> 1) & 3);
            gload16(Ag + (long)(bm + m) * lda + k0 + qg * 8,
                    &As[(is * 256 + wv * 64) * 8]);
        }
        if constexpr (ACH % 256) {
            if (tid < ACH % 256) {
                int c = (ACH / 256) * 256 + tid;
                int m = c >> 2, kq = c & 3;
                int qg = kq ^ ((m >> 1) & 3);
                gload16(Ag + (long)(bm + m) * lda + k0 + qg * 8,
                        &As[((ACH / 256) * 256 + wv * 64) * 8]);
            }
        }
        #pragma unroll
        for (int is = 0; is < BCH / 256; ++is) {
            int c = is * 256 + wv * 64 + ln;
            int m = c >> 2, kq = c & 3;
            int qg = kq ^ ((m >> 1) & 3);
            gload16(Bg + (long)(bn + m) * ldb + k0 + qg * 8,
                    &Bs[(is * 256 + wv * 64) * 8]);
        }
        if constexpr (BCH % 256) {
            if (tid < BCH % 256) {
                int c = (BCH / 256) * 256 + tid;
                int m = c >> 2, kq = c & 3;
                int qg = kq ^ ((m >> 1) & 3);
                gload16(Bg + (long)(bn + m) * ldb + k0 + qg * 8,
                        &Bs[((BCH / 256) * 256 + wv * 64) * 8]);
            }
        }
        __syncthreads();
        s8v av[WM], bv[WN];
        #pragma unroll
        for (int i = 0; i < WM; ++i) {
            int row = wr * (WM * 16) + i * 16 + fr;
            av[i] = *(const s8v*)&As[row * 32 + (fq ^ ((row >> 1) & 3)) * 8];
        }
        #pragma unroll
        for (int j = 0; j < WN; ++j) {
            int row = wc * (WN * 16) + j * 16 + fr;
            bv[j] = *(const s8v*)&Bs[row * 32 + (fq ^ ((row >> 1) & 3)) * 8];
        }
        #pragma unroll
        for (int i = 0; i < WM; ++i)
            #pragma unroll
            for (int j = 0; j < WN; ++j)
                acc[i][j] = __builtin_amdgcn_mfma_f32_16x16x32_bf16(av[i], bv[j], acc[i][j], 0, 0, 0);
        __syncthreads();
    }

    #pragma unroll
    for (int i = 0; i < WM; ++i) {
        #pragma unroll
        for (int r = 0; r < 4; ++r) {
            int row = bm + wr * (WM * 16) + i * 16 + fq * 4 + r;
            if (GROUPED && row >= m_count) continue;
            #pragma unroll
            for (int j = 0; j < WN; ++j) {
                int col = bn + wc * (WN * 16) + j * 16 + fr;
                if (col < N) {
                    float v = acc[i][j][r] * alpha;
                    if (OUTMODE == 2) {
                        atomicAdd(&Cf[(long)row * ldc + col], v);
                    } else {
                        if (biasp) v += biasp[col];
                        if (GELU) v = 0.5f * v * (1.f + erff(v * 0.70710678118654752f));
                        if (resid) v += resid[(long)row * ldc + col];
                        if (OUTMODE == 1) Cb[(long)row * ldc + col] = __float2bfloat16(v);
                        else              Cf[(long)row * ldc + col] = v;
                    }
                }
            }
        }
    }
}

// Standalone wrapper (PV, out-proj)
template<int WM, int WN, bool GROUPED, bool GELU, int OUTMODE>
__global__ __launch_bounds__(256) void mfma_gemm(
    const bf16* A, const bf16* B, const float* bias, const float* resid,
    void* Cv, int M, int N, int K, int lda, int ldb, int ldc,
    int zdiv, int ksplit,
    long a_hi, long a_lo, long b_hi, long b_lo, long c_hi, long c_lo,
    long bias_stride, const int* grp_off, float alpha)
{
    __shared__ char smem[(32 * WM + 32 * WN) * 32 * 2];
    dev_mfma_gemm<WM, WN, GROUPED, GELU, OUTMODE>(
        A, B, bias, resid, Cv, M, N, K, lda, ldb, ldc, zdiv, ksplit,
        a_hi, a_lo, b_hi, b_lo, c_hi, c_lo, bias_stride, grp_off, alpha,
        blockIdx.x, blockIdx.y, blockIdx.z, smem);
}

// ---------------- weight transpose-convert tile (blocked output) -------------
// id<4608: w1 (K=768, C=3072); else w2 (K=3072, C=768).
// Output bf16 chunk-blocked [K/8][C][8]. Needs 64*65*4 = 16640B of smem.
__device__ __forceinline__ void dev_wtrans(int id,
                                           const float* __restrict__ w1,
                                           bf16* __restrict__ w1t,
                                           const float* __restrict__ w2,
                                           bf16* __restrict__ w2t,
                                           char* smem) {
    const float* in; bf16* out; int C, e, ct, rt;
    if (id < 4608) {                     // w1: 8 x (48 ct x 12 rt)
        e = id / 576; int rem = id % 576; ct = rem / 12; rt = rem % 12;
        in = w1; out = w1t; C = FFDIM;
    } else {
        id -= 4608;                      // w2: 8 x (12 ct x 48 rt)
        e = id / 576; int rem = id % 576; ct = rem / 48; rt = rem % 48;
        in = w2; out = w2t; C = DIM;
    }
    long ibase = (long)e * DIM * FFDIM;
    int rt0 = rt * 64, ct0 = ct * 64;
    float (*tile)[65] = (float(*)[65])smem;
    int t = threadIdx.x;
    {
        int q = t >> 4, cq = t & 15;
        #pragma unroll
        for (int i = 0; i < 4; ++i) {
            int row = q + i * 16;
            float4 v = *(const float4*)&in[ibase + (long)(rt0 + row) * C + ct0 + cq * 4];
            tile[row][cq * 4]     = v.x;
            tile[row][cq * 4 + 1] = v.y;
            tile[row][cq * 4 + 2] = v.z;
            tile[row][cq * 4 + 3] = v.w;
        }
    }
    __syncthreads();
    {
        int kb2 = t >> 6, n = t & 63;
        #pragma unroll
        for (int i = 0; i < 2; ++i) {
            int kblk = kb2 + 4 * i;
            unsigned w[4];
            #pragma unroll
            for (int j = 0; j < 4; ++j) {
                w[j] = ((unsigned)bf16bits(tile[kblk * 8 + 2 * j + 1][n]) << 16)
                     | bf16bits(tile[kblk * 8 + 2 * j][n]);
            }
            uint4 u; u.x = w[0]; u.y = w[1]; u.z = w[2]; u.w = w[3];
            *(uint4*)&out[ibase + ((long)(rt0 >> 3) + kblk) * C * 8 + (long)(ct0 + n) * 8] = u;
        }
    }
}

// ---------------- fused: qkv GEMM + w1 transpose (INTERLEAVED block map) ------
__global__ __launch_bounds__(256) void qkv_w1_kernel(
    const bf16* __restrict__ h_b, const bf16* __restrict__ in_wb,
    const float* __restrict__ in_b, bf16* __restrict__ qkv_b,
    const float* __restrict__ w1, bf16* __restrict__ w1t,
    const float* __restrict__ w2, bf16* __restrict__ w2t) {
    __shared__ char smem[16640];
    int bid = blockIdx.x;
    if (bid % 9 == 0) {
        int g = bid / 9;                               // 0..575
        dev_mfma_gemm<2, 2, false, false, 1>(
            h_b, in_wb, in_b, nullptr, qkv_b,
            NTOK, 3 * DIM, DIM, DIM, DIM, 3 * DIM,
            1, 1, 0, 0, 0, 0, 0, 0, 0, nullptr, 1.f,
            g % 36, g / 36, 0, smem);
    } else {
        int tr = bid - bid / 9 - 1;                    // 0..4607 = w1 ids
        dev_wtrans(tr, w1, w1t, w2, w2t, smem);
    }
}

// ---------------- fused: scores GEMM + w2 transpose (INTERLEAVED) -------------
__global__ __launch_bounds__(256) void scores_w2_kernel(
    const bf16* __restrict__ qkv_b, bf16* __restrict__ scores,
    const float* __restrict__ w1, bf16* __restrict__ w1t,
    const float* __restrict__ w2, bf16* __restrict__ w2t) {
    __shared__ char smem[16640];
    int bid = blockIdx.x;
    if (bid % 7 == 0) {
        int g = bid / 7;                               // 0..767
        dev_mfma_gemm<2, 4, false, false, 1>(
            qkv_b, qkv_b + DIM, nullptr, nullptr, scores,
            SEQ, SEQ, HDIM, 3 * DIM, 3 * DIM, SEQ,
            HEADS, 1, (long)SEQ * 3 * DIM, HDIM, (long)SEQ * 3 * DIM, HDIM,
            (long)HEADS * SEQ * SEQ, (long)SEQ * SEQ,
            0, nullptr, 0.125f,
            g % 4, (g >> 2) & 7, g >> 5, smem);
    } else {
        int tr = bid - bid / 7 - 1;                    // 0..4607 -> w2 ids
        dev_wtrans(4608 + tr, w1, w1t, w2, w2t, smem);
    }
}

// ---------------- MoE grouped GEMM v12: chunk-blocked B layout ----------------
template<int FM, int FN, int XT, int YCAP, int KS, bool GELU, int OUTMODE, bool GATHER>
__global__ __launch_bounds__(256) void moe_gemm(
    const bf16* __restrict__ A, const bf16* __restrict__ B,
    const float* __restrict__ bias, void* __restrict__ Cv,
    int lda, int Nt, int ldc, int Ktot, long b_hi, long bias_stride,
    const int* __restrict__ grp_off, const int* __restrict__ entry_tok,
    int N, long pstride)
{
    static_assert(OUTMODE != 1 || KS == 1, "plain bf16 store requires no split-K");
    constexpr int BM = FM * 32, BN = FN * 32;
    constexpr int GA = BM / 64;
    constexpr int GB = BN / 64;
    constexpr int G = GA + GB;

    int bid = blockIdx.x;
    int e = bid & 7;
    int r = bid >> 3;
    int xt = r % XT; r /= XT;
    int yt = r % YCAP;
    int ks = r / YCAP;
    int m0 = grp_off[e], m1 = grp_off[e + 1];
    int m_count = m1 - m0;
    int bm = yt * BM;
    if (bm >= m_count) return;
    int bn = xt * BN;
    int kper = Ktot / KS;

    const short* Ag = (const short*)A + (GATHER ? 0 : (long)m0 * lda);
    const short* Bg = (const short*)(B + (long)e * b_hi);
    const float* biasp = bias ? bias + (long)e * bias_stride : nullptr;
    float* Cf = (float*)Cv + (long)m0 * ldc + (long)ks * pstride;
    bf16*  Cb = (bf16*)Cv + (long)m0 * ldc;

    __shared__ short As[3][BM * 32];
    __shared__ short Bs[3][BN * 32];

    int tid = threadIdx.x;
    int wv = tid >> 6, ln = tid & 63;
    int wr = wv >> 1, wc = wv & 1;
    int fr = ln & 15, fq = ln >> 4;

    long arow[GA];
    #pragma unroll
    for (int is = 0; is < GA; ++is) {
        int c = is * 256 + wv * 64 + ln;
        int m = c >> 2;
        if (GATHER) {
            int gi = m0 + bm + m;
            arow[is] = (long)entry_tok[gi < NENT ? gi : NENT - 1] * lda;
        } else {
            arow[is] = (long)(bm + m) * lda;
        }
    }

    f4v acc[FM][FN] = {};

    auto stage = [&](int buf, int k0) {
        #pragma unroll
        for (int is = 0; is < GA; ++is) {
            int c = is * 256 + wv * 64 + ln;
            int m = c >> 2, q = c & 3;
            int qg = q ^ ((m >> 1) & 3);
            gload16(Ag + arow[is] + k0 + qg * 8,
                    &As[buf][(is * 256 + wv * 64) * 8]);
        }
        #pragma unroll
        for (int is = 0; is < GB; ++is) {
            int c = is * 256 + wv * 64 + ln;
            int n = c >> 2, q = c & 3;
            int qg = q ^ ((n >> 1) & 3);
            gload16(Bg + ((long)(k0 >> 3) + qg) * Nt * 8 + (long)(bn + n) * 8,
                    &Bs[buf][(is * 256 + wv * 64) * 8]);
        }
    };

    int kbeg = ks * kper;
    int nit = kper / 32;
    stage(0, kbeg);
    if (nit > 1) stage(1, kbeg + 32);

    for (int it = 0; it < nit; ++it) {
        if (it + 1 < nit) asm volatile("s_waitcnt vmcnt(%0)" :: "i"(G) : "memory");
        else              asm volatile("s_waitcnt vmcnt(0)" ::: "memory");
        __builtin_amdgcn_s_barrier();
        if (it + 2 < nit) stage((it + 2) % 3, kbeg + (it + 2) * 32);
        int cur = it % 3;
        __builtin_amdgcn_s_setprio(1);
        {
            s8v av[FM], bv[FN];
            #pragma unroll
            for (int i = 0; i < FM; ++i) {
                int row = wr * (FM * 16) + i * 16 + fr;
                av[i] = *(const s8v*)&As[cur][row * 32 + (fq ^ ((row >> 1) & 3)) * 8];
            }
            #pragma unroll
            for (int j = 0; j < FN; ++j) {
                int row = wc * (FN * 16) + j * 16 + fr;
                bv[j] = *(const s8v*)&Bs[cur][row * 32 + (fq ^ ((row >> 1) & 3)) * 8];
            }
            #pragma unroll
            for (int i = 0; i < FM; ++i)
                #pragma unroll
                for (int j = 0; j < FN; ++j)
                    acc[i][j] = __builtin_amdgcn_mfma_f32_16x16x32_bf16(av[i], bv[j], acc[i][j], 0, 0, 0);
        }
        __builtin_amdgcn_s_setprio(0);
    }

    #pragma unroll
    for (int i = 0; i < FM; ++i) {
        #pragma unroll
        for (int rr = 0; rr < 4; ++rr) {
            int row = bm + wr * (FM * 16) + i * 16 + fq * 4 + rr;
            if (row >= m_count) continue;
            #pragma unroll
            for (int j = 0; j < FN; ++j) {
                int col = bn + wc * (FN * 16) + j * 16 + fr;
                float v = acc[i][j][rr];
                if (OUTMODE == 0) {
                    Cf[(long)row * ldc + col] = v;
                } else {
                    if (biasp) v += biasp[col];
                    if (GELU) v = 0.5f * v * (1.f + erff(v * 0.70710678118654752f));
                    Cb[(long)row * ldc + col] = __float2bfloat16(v);
                }
            }
        }
    }
}

// ---------------- fused: softmax (3072 blocks) + V transpose (192 blocks) ----
__global__ __launch_bounds__(256) void softmax_vt_kernel(
    const bf16* __restrict__ s, bf16* __restrict__ attn,
    const bf16* __restrict__ qkvb, bf16* __restrict__ vt) {
    __shared__ short tile[64][65];
    int bid = blockIdx.x;
    int t = threadIdx.x;
    if (bid < 3072) {                    // softmax: wave per row
        long row = (long)bid * 4 + (t >> 6);
        int ln = t & 63;
        const unsigned* p = (const unsigned*)(s + row * 512);
        uint4 v = *(const uint4*)(p + ln * 4);
        unsigned u[4] = {v.x, v.y, v.z, v.w};
        float f[8];
        #pragma unroll
        for (int j = 0; j < 4; ++j) {
            f[2*j]   = bfbits2f(u[j] << 16);
            f[2*j+1] = bfbits2f(u[j] & 0xffff0000u);
        }
        float m = f[0];
        #pragma unroll
        for (int j = 1; j < 8; ++j) m = fmaxf(m, f[j]);
        #pragma unroll
        for (int o = 32; o; o >>= 1) m = fmaxf(m, __shfl_xor(m, o));
        float e[8], ssum = 0.f;
        #pragma unroll
        for (int j = 0; j < 8; ++j) { e[j] = expf(f[j] - m); ssum += e[j]; }
        #pragma unroll
        for (int o = 32; o; o >>= 1) ssum += __shfl_xor(ssum, o);
        float inv = 1.f / ssum;
        unsigned w[4];
        #pragma unroll
        for (int j = 0; j < 4; ++j) {
            bf16 lo = __float2bfloat16(e[2*j] * inv);
            bf16 hi = __float2bfloat16(e[2*j+1] * inv);
            w[j] = ((unsigned)*(unsigned short*)&hi << 16) | *(unsigned short*)&lo;
        }
        uint4 o4; o4.x = w[0]; o4.y = w[1]; o4.z = w[2]; o4.w = w[3];
        *(uint4*)((unsigned*)(attn + row * 512) + ln * 4) = o4;
    } else {                             // V transpose
        int id = bid - 3072;             // 0..191
        int st = id % 8;
        int z = id / 8;
        int b = z / HEADS, h = z % HEADS;
        int d = t & 63, s0 = t >> 6;
        const short* q = (const short*)qkvb;
        #pragma unroll
        for (int i = 0; i < 16; ++i) {
            int sq = st * 64 + s0 + i * 4;
            tile[s0 + i * 4][d] = q[(long)(b * SEQ + sq) * 2304 + 2 * DIM + h * HDIM + d];
        }
        __syncthreads();
        short* o = (short*)vt;
        #pragma unroll
        for (int i = 0; i < 16; ++i) {
            int d2 = (t >> 6) + i * 4;
            o[(long)(z * 64 + d2) * 512 + st * 64 + (t & 63)] = tile[t & 63][d2];
        }
    }
}

// ---------------- router: logits, softmax, top2, renorm ----------------
__global__ __launch_bounds__(64) void router_kernel(const float* __restrict__ t2,
                                                    const float* __restrict__ rw,
                                                    const float* __restrict__ rb,
                                                    int* __restrict__ e_sel,
                                                    float* __restrict__ w_sel) {
    int t = blockIdx.x;
    int lane = threadIdx.x;
    const float* tr = t2 + (long)t * DIM;
    float tv[12];
    #pragma unroll
    for (int i = 0; i < 12; ++i) tv[i] = tr[lane + 64 * i];
    float logits[NEXP];
    #pragma unroll
    for (int e = 0; e < NEXP; ++e) {
        const float* wr = rw + (long)e * DIM;
        float s = 0.f;
        #pragma unroll
        for (int i = 0; i < 12; ++i) s += tv[i] * wr[lane + 64 * i];
        #pragma unroll
        for (int o = 32; o; o >>= 1) s += __shfl_xor(s, o);
        logits[e] = s + rb[e];
    }
    if (lane == 0) {
        int e0 = -1, e1 = -1;
        float l0 = -1e30f, l1 = -1e30f;
        #pragma unroll
        for (int e = 0; e < NEXP; ++e) {
            float l = logits[e];
            if (l > l0) { l1 = l0; e1 = e0; l0 = l; e0 = e; }
            else if (l > l1) { l1 = l; e1 = e; }
        }
        float p1 = expf(l1 - l0);
        float inv = 1.f / (1.f + p1);
        e_sel[t * 2] = e0;  e_sel[t * 2 + 1] = e1;
        w_sel[t * 2] = inv; w_sel[t * 2 + 1] = p1 * inv;
    }
}

// ---------------- build per-expert entry lists (single block) ----------------
__global__ __launch_bounds__(1024) void build_lists(const int* __restrict__ e_sel,
                                                    int* __restrict__ entry_tok,
                                                    int* __restrict__ pos,
                                                    int* __restrict__ grp_off) {
    __shared__ int cnt[NEXP];
    __shared__ int off[NEXP + 1];
    __shared__ int cur[NEXP];
    int tid = threadIdx.x;
    if (tid < NEXP) cnt[tid] = 0;
    __syncthreads();
    for (int i = tid; i < NENT; i += 1024) atomicAdd(&cnt[e_sel[i]], 1);
    __syncthreads();
    if (tid == 0) {
        off[0] = 0;
        for (int e = 0; e < NEXP; ++e) off[e + 1] = off[e] + cnt[e];
        for (int e = 0; e < NEXP; ++e) cur[e] = off[e];
    }
    __syncthreads();
    for (int i = tid; i < NENT; i += 1024) {
        int e = e_sel[i];
        int p = atomicAdd(&cur[e], 1);
        entry_tok[p] = i >> 1;
        pos[i] = p;
    }
    if (tid < NEXP + 1) grp_off[tid] = off[tid];
}

// ---------------- final combine (float4): out = x1 + sum_s w_s*(b2+sum parts) -
__global__ __launch_bounds__(256) void combine_kernel(const float* __restrict__ x1,
                                                      const float* __restrict__ ypart,
                                                      const float* __restrict__ b2,
                                                      const int* __restrict__ pos,
                                                      const int* __restrict__ e_sel,
                                                      const float* __restrict__ wsel,
                                                      float* __restrict__ out) {
    long i4 = (long)blockIdx.x * 256 + threadIdx.x;      // float4 units; 196608 total
    if (i4 >= (long)NTOK * DIM / 4) return;
    int t = (int)(i4 / 192), d4 = (int)(i4 % 192);
    const float4* x1v = (const float4*)x1;
    const float4* ypv = (const float4*)ypart;
    const float4* b2v = (const float4*)b2;
    float4 v = x1v[i4];
    #pragma unroll
    for (int s = 0; s < 2; ++s) {
        long base = (long)pos[t * 2 + s] * 192 + d4;
        float4 y = b2v[(long)e_sel[t * 2 + s] * 192 + d4];
        #pragma unroll
        for (int ks = 0; ks < 4; ++ks) {
            float4 pp = ypv[base + ks * (YPS / 4)];
            y.x += pp.x; y.y += pp.y; y.z += pp.z; y.w += pp.w;
        }
        float w = wsel[t * 2 + s];
        v.x += w * y.x; v.y += w * y.y; v.z += w * y.z; v.w += w * y.w;
    }
    ((float4*)out)[i4] = v;
}

extern "C" void kernel_launch(void* const* d_in, const int* in_sizes, int n_in,
                              void* d_out, int out_size, void* d_ws, size_t ws_size,
                              hipStream_t stream) {
    const float* x        = (const float*)d_in[0];
    const float* ln1_g    = (const float*)d_in[1];
    const float* ln1_b    = (const float*)d_in[2];
    const float* ln2_g    = (const float*)d_in[3];
    const float* ln2_b    = (const float*)d_in[4];
    const float* in_w     = (const float*)d_in[5];
    const float* in_b     = (const float*)d_in[6];
    const float* out_w    = (const float*)d_in[7];
    const float* out_b    = (const float*)d_in[8];
    const float* router_w = (const float*)d_in[9];
    const float* router_b = (const float*)d_in[10];
    const float* w1       = (const float*)d_in[11];
    const float* b1       = (const float*)d_in[12];
    const float* w2       = (const float*)d_in[13];
    const float* b2       = (const float*)d_in[14];
    float* out = (float*)d_out;

    const long TD = (long)NTOK * DIM;
    char* p = (char*)d_ws;
    size_t off = 0;
    auto alloc = [&](size_t bytes) -> void* {
        void* r = p + off; off += (bytes + 255) & ~(size_t)255; return r;
    };
    bf16*  h_b    = (bf16*)alloc(TD * 2);
    bf16*  in_wb  = (bf16*)alloc(2304L * 768 * 2);
    bf16*  qkv_b  = (bf16*)alloc(1024L * 2304 * 2);
    bf16*  out_wb = (bf16*)alloc(768L * 768 * 2);
    bf16*  vt_b   = (bf16*)alloc((24L * 64 + 64) * 512 * 2);
    bf16*  oat_b  = (bf16*)alloc(TD * 2);
    float* opart  = (float*)alloc(2 * TD * 4);                 // out-proj K-partials
    float* x1     = (float*)alloc(TD * 4);
    float* t2     = (float*)alloc(TD * 4);
    bf16*  t2b    = (bf16*)alloc((NTOK + 256L) * DIM * 2);     // +pad (BM overread)
    bf16*  w1t    = (bf16*)alloc(8L * 3072 * 768 * 2);
    bf16*  w2t    = (bf16*)alloc(8L * 768 * 3072 * 2);
    bf16*  scores = (bf16*)alloc(24L * 512 * 512 * 2);
    bf16*  attn   = (bf16*)alloc(24L * 512 * 512 * 2);
    bf16*  hid    = (bf16*)alloc((2048L + 256) * 3072 * 2);    // +pad
    float* ypart  = (float*)alloc(4 * YPS * 4);                // 4 split-K partials
    int*   e_sel     = (int*)alloc(NENT * 4);
    float* w_sel     = (float*)alloc(NENT * 4);
    int*   entry_tok = (int*)alloc(NENT * 4);
    int*   pos       = (int*)alloc(NENT * 4);
    int*   grp_off   = (int*)alloc(64);

    // 1. FUSED: LN1 (1024 blocks, float4) + attention weight cvt (2304 blocks)
    ln1_cvt_kernel<<<NTOK + 2304, 256, 0, stream>>>(
        x, ln1_g, ln1_b, h_b,
        in_w, 2304L * 768, out_w, 768L * 768, in_wb, out_wb);
    // 2. FUSED+INTERLEAVED: qkv GEMM (576) + w1 transpose (4608)
    qkv_w1_kernel<<<576 + 4608, 256, 0, stream>>>(h_b, in_wb, in_b, qkv_b,
                                                  w1, w1t, w2, w2t);
    // 3. FUSED+INTERLEAVED: scores GEMM (768) + w2 transpose (4608)
    scores_w2_kernel<<<768 + 4608, 256, 0, stream>>>(qkv_b, scores,
                                                     w1, w1t, w2, w2t);
    // 4. FUSED: softmax (3072) + V transpose (192)
    softmax_vt_kernel<<<3072 + 192, 256, 0, stream>>>(scores, attn, qkv_b, vt_b);
    // 5. o = attn @ V -> oat bf16   BM=32: 384 blocks
    mfma_gemm<1, 2, false, false, 1><<<dim3(1, 16, 24), 256, 0, stream>>>(
        attn, vt_b, nullptr, nullptr, oat_b,
        SEQ, HDIM, SEQ, SEQ, SEQ, DIM,
        HEADS, 1, (long)HEADS * SEQ * SEQ, (long)SEQ * SEQ,
        (long)HEADS * HDIM * SEQ, (long)HDIM * SEQ,
        (long)SEQ * DIM, HDIM,
        0, nullptr, 1.f);
    // 6. out-proj split-K x2, plain partial stores
    mfma_gemm<2, 2, false, false, 0><<<dim3(12, 16, 2), 256, 0, stream>>>(
        oat_b, out_wb, nullptr, nullptr, opart,
        NTOK, DIM, 384, DIM, DIM, DIM,
        2, 1, 0, 384, 0, 384, 0, TD, 0, nullptr, 1.f);
    // 7. LN2 fused with x1 assembly (float4)
    ln2x1_kernel<<<NTOK, 256, 0, stream>>>(x, out_b, opart, ln2_g, ln2_b,
                                           x1, t2, t2b);
    // 8. router
    router_kernel<<<NTOK, 64, 0, stream>>>(t2, router_w, router_b, e_sel, w_sel);
    // 9. build lists
    build_lists<<<1, 1024, 0, stream>>>(e_sel, entry_tok, pos, grp_off);
    // 10. FFN1 grouped, GATHER-fused A: hid = gelu(t2b[tok] @ w1 + b1) -> bf16
    moe_gemm<4, 4, 24, 8, 1, true, 1, true><<<8 * 24 * 8, 256, 0, stream>>>(
        t2b, w1t, b1, hid,
        DIM, FFDIM, FFDIM, DIM, (long)FFDIM * DIM, FFDIM, grp_off, entry_tok,
        FFDIM, 0);
    // 11. FFN2 grouped split-K x4, plain partial stores
    moe_gemm<4, 4, 6, 8, 4, false, 0, false><<<8 * 6 * 8 * 4, 256, 0, stream>>>(
        hid, w2t, nullptr, ypart,
        FFDIM, DIM, DIM, FFDIM, (long)FFDIM * DIM, 0, grp_off, nullptr,
        DIM, YPS);
    // 12. combine (float4)
    combine_kernel<<<768, 256, 0, stream>>>(x1, ypart, b2, pos, e_sel, w_sel, out);
}

// Round 24
// 179.544 us; speedup vs baseline: 1.0391x; 1.0023x over previous
//
#include <hip/hip_runtime.h>
#include <hip/hip_bf16.h>

// Problem constants
#define BATCH 2
#define SEQ 512
#define DIM 768
#define HEADS 12
#define NEXP 8
#define FFDIM 3072
#define HDIM 64
#define NTOK (BATCH*SEQ)          // 1024
#define NENT (2*NTOK)             // 2048 (token, slot) entries
#define YPS ((long)NENT * DIM)    // partial-buffer stride

typedef __hip_bfloat16 bf16;
typedef __attribute__((ext_vector_type(8))) short s8v;
typedef __attribute__((ext_vector_type(4))) float f4v;

// ---- async global->LDS (16B per lane, wave-uniform LDS base + lane*16) ----
typedef __attribute__((address_space(1))) const unsigned char gas_u8;
typedef __attribute__((address_space(3))) unsigned char las_u8;
__device__ __forceinline__ void gload16(const void* g, void* l) {
    __builtin_amdgcn_global_load_lds((gas_u8*)g, (las_u8*)l, 16, 0, 0);
}

__device__ __forceinline__ float bfbits2f(unsigned hi16) {
    union { unsigned u; float f; } c; c.u = hi16; return c.f;
}
__device__ __forceinline__ unsigned short bf16bits(float f) {
    bf16 h = __float2bfloat16(f);
    return *reinterpret_cast<unsigned short*>(&h);
}
__device__ __forceinline__ uint2 pack4bf(float a, float b, float c, float d) {
    uint2 u;
    u.x = ((unsigned)bf16bits(b) << 16) | bf16bits(a);
    u.y = ((unsigned)bf16bits(d) << 16) | bf16bits(c);
    return u;
}

// ---------------- LN1 (vectorized) + weight cvt, fused ----------------
// blocks 0..1023: LN1 over x -> h_b (bf16). blocks 1024..3327: cvt in_w/out_w.
__global__ __launch_bounds__(256) void ln1_cvt_kernel(
    const float* __restrict__ x, const float* __restrict__ g,
    const float* __restrict__ b, bf16* __restrict__ outb,
    const float* __restrict__ wa, long na, const float* __restrict__ wb, long nb,
    bf16* __restrict__ oa, bf16* __restrict__ ob2) {
    int bid = blockIdx.x;
    int tid = threadIdx.x;
    if (bid >= NTOK) {                   // cvt part
        long i = ((long)(bid - NTOK) * 256 + tid) * 4;
        const float* src; bf16* dst; long idx;
        if (i < na) { src = wa; dst = oa; idx = i; }
        else if (i < na + nb) { src = wb; dst = ob2; idx = i - na; }
        else return;
        float4 v = *(const float4*)(src + idx);
        *(uint2*)(dst + idx) = pack4bf(v.x, v.y, v.z, v.w);
        return;
    }
    // LN1, float4 path: 192 active lanes
    long base4 = (long)bid * 192;
    float4 v = {0.f, 0.f, 0.f, 0.f};
    if (tid < 192) v = ((const float4*)x)[base4 + tid];
    float s = v.x + v.y + v.z + v.w;
    __shared__ float red[4];
    #pragma unroll
    for (int o = 32; o; o >>= 1) s += __shfl_xor(s, o);
    if ((tid & 63) == 0) red[tid >> 6] = s;
    __syncthreads();
    s = red[0] + red[1] + red[2] + red[3];
    float mu = s * (1.f / DIM);
    float4 d = {v.x - mu, v.y - mu, v.z - mu, v.w - mu};
    float q = (tid < 192) ? (d.x*d.x + d.y*d.y + d.z*d.z + d.w*d.w) : 0.f;
    __shared__ float red2[4];
    #pragma unroll
    for (int o = 32; o; o >>= 1) q += __shfl_xor(q, o);
    if ((tid & 63) == 0) red2[tid >> 6] = q;
    __syncthreads();
    q = red2[0] + red2[1] + red2[2] + red2[3];
    float rstd = rsqrtf(q * (1.f / DIM) + 1e-5f);
    if (tid < 192) {
        float4 g4 = ((const float4*)g)[tid];
        float4 b4 = ((const float4*)b)[tid];
        ((uint2*)outb)[base4 + tid] = pack4bf(
            d.x * rstd * g4.x + b4.x, d.y * rstd * g4.y + b4.y,
            d.z * rstd * g4.z + b4.z, d.w * rstd * g4.w + b4.w);
    }
}

// ---------------- LN2 + x1 assembly + ROUTER, fully fused ----------------
// x1 = x + out_b + opart0 + opart1 ; t2b = LN(x1) (bf16) ;
// router logits from the in-register LN row -> top-2 -> e_sel/w_sel.
__global__ __launch_bounds__(256) void ln2x1r_kernel(
    const float* __restrict__ x, const float* __restrict__ out_b,
    const float* __restrict__ op, const float* __restrict__ g,
    const float* __restrict__ b, const float* __restrict__ rw,
    const float* __restrict__ rb, float* __restrict__ x1,
    bf16* __restrict__ t2b, int* __restrict__ e_sel,
    float* __restrict__ w_sel) {
    int t = blockIdx.x;
    int tid = threadIdx.x;
    const long TD4 = (long)NTOK * DIM / 4;
    long base4 = (long)t * 192;
    float4 v = {0.f, 0.f, 0.f, 0.f};
    if (tid < 192) {
        long i4 = base4 + tid;
        float4 xv = ((const float4*)x)[i4];
        float4 ob = ((const float4*)out_b)[tid];
        float4 o0 = ((const float4*)op)[i4];
        float4 o1 = ((const float4*)op)[i4 + TD4];
        v.x = xv.x + ob.x + o0.x + o1.x;
        v.y = xv.y + ob.y + o0.y + o1.y;
        v.z = xv.z + ob.z + o0.z + o1.z;
        v.w = xv.w + ob.w + o0.w + o1.w;
        ((float4*)x1)[i4] = v;
    }
    float s = v.x + v.y + v.z + v.w;
    __shared__ float red[4];
    #pragma unroll
    for (int o = 32; o; o >>= 1) s += __shfl_xor(s, o);
    if ((tid & 63) == 0) red[tid >> 6] = s;
    __syncthreads();
    s = red[0] + red[1] + red[2] + red[3];
    float mu = s * (1.f / DIM);
    float4 d = {v.x - mu, v.y - mu, v.z - mu, v.w - mu};
    float q = (tid < 192) ? (d.x*d.x + d.y*d.y + d.z*d.z + d.w*d.w) : 0.f;
    __shared__ float red2[4];
    #pragma unroll
    for (int o = 32; o; o >>= 1) q += __shfl_xor(q, o);
    if ((tid & 63) == 0) red2[tid >> 6] = q;
    __syncthreads();
    q = red2[0] + red2[1] + red2[2] + red2[3];
    float rstd = rsqrtf(q * (1.f / DIM) + 1e-5f);
    float4 ov = {0.f, 0.f, 0.f, 0.f};
    if (tid < 192) {
        float4 g4 = ((const float4*)g)[tid];
        float4 b4 = ((const float4*)b)[tid];
        ov.x = d.x * rstd * g4.x + b4.x;
        ov.y = d.y * rstd * g4.y + b4.y;
        ov.z = d.z * rstd * g4.z + b4.z;
        ov.w = d.w * rstd * g4.w + b4.w;
        ((uint2*)t2b)[base4 + tid] = pack4bf(ov.x, ov.y, ov.z, ov.w);
    }
    // Router: 8 logits via block-wide dot products with the in-register row.
    float part[NEXP];
    #pragma unroll
    for (int e = 0; e < NEXP; ++e) {
        float pv = 0.f;
        if (tid < 192) {
            float4 w4 = ((const float4*)rw)[(long)e * 192 + tid];
            pv = ov.x * w4.x + ov.y * w4.y + ov.z * w4.z + ov.w * w4.w;
        }
        part[e] = pv;
    }
    __shared__ float rred[4][NEXP];
    #pragma unroll
    for (int e = 0; e < NEXP; ++e) {
        float pv = part[e];
        #pragma unroll
        for (int o = 32; o; o >>= 1) pv += __shfl_xor(pv, o);
        if ((tid & 63) == 0) rred[tid >> 6][e] = pv;
    }
    __syncthreads();
    if (tid == 0) {
        float logits[NEXP];
        #pragma unroll
        for (int e = 0; e < NEXP; ++e)
            logits[e] = rred[0][e] + rred[1][e] + rred[2][e] + rred[3][e] + rb[e];
        int e0 = -1, e1 = -1;
        float l0 = -1e30f, l1 = -1e30f;
        #pragma unroll
        for (int e = 0; e < NEXP; ++e) {
            float l = logits[e];
            if (l > l0) { l1 = l0; e1 = e0; l0 = l; e0 = e; }
            else if (l > l1) { l1 = l; e1 = e; }
        }
        float p1 = expf(l1 - l0);
        float inv = 1.f / (1.f + p1);
        e_sel[t * 2] = e0;  e_sel[t * 2 + 1] = e1;
        w_sel[t * 2] = inv; w_sel[t * 2 + 1] = p1 * inv;
    }
}

// ---------------- MFMA GEMM device body (attention-side) ----------------
template<int WM, int WN, bool GROUPED, bool GELU, int OUTMODE>
__device__ __forceinline__ void dev_mfma_gemm(
    const bf16* __restrict__ A, const bf16* __restrict__ B,
    const float* __restrict__ bias, const float* __restrict__ resid,
    void* __restrict__ Cv,
    int M, int N, int K, int lda, int ldb, int ldc,
    int zdiv, int ksplit,
    long a_hi, long a_lo, long b_hi, long b_lo, long c_hi, long c_lo,
    long bias_stride, const int* __restrict__ grp_off, float alpha,
    int bx, int by, int bz, char* smem)
{
    constexpr int BM = 32 * WM, BN = 32 * WN;
    constexpr int ACH = BM * 4;     // 16B chunks in A tile
    constexpr int BCH = BN * 4;

    int z = bz;
    int ze = z / ksplit, ks = z % ksplit;
    int kper = K / ksplit;
    long aoff, boff, coff;
    int m_count = M;
    if (GROUPED) {
        int m0 = grp_off[ze], m1 = grp_off[ze + 1];
        m_count = m1 - m0;
        if (by * BM >= m_count) return;
        aoff = (long)m0 * lda;
        coff = (long)m0 * ldc;
        boff = (long)ze * b_hi;
    } else {
        int zh = ze / zdiv, zl = ze % zdiv;
        aoff = zh * a_hi + zl * a_lo;
        boff = zh * b_hi + zl * b_lo;
        coff = zh * c_hi + zl * c_lo;
    }
    const short* Ag = (const short*)(A + aoff);
    const short* Bg = (const short*)(B + boff);
    const float* biasp = bias ? bias + (long)ze * bias_stride : nullptr;
    float* Cf = (float*)Cv + coff;
    bf16*  Cb = (bf16*)Cv + coff;

    short* As = (short*)smem;
    short* Bs = As + BM * 32;

    int tid = threadIdx.x;
    int wv = tid >> 6, ln = tid & 63;
    int wr = wv >> 1, wc = wv & 1;
    int fr = ln & 15, fq = ln >> 4;
    int bm = by * BM, bn = bx * BN;

    f4v acc[WM][WN] = {};

    for (int k0 = ks * kper; k0 < (ks + 1) * kper; k0 += 32) {
        #pragma unroll
        for (int is = 0; is < ACH / 256; ++is) {
            int c = is * 256 + wv * 64 + ln;
            int m = c >> 2, kq = c & 3;
            int qg = kq ^ ((m >> 1) & 3);
            gload16(Ag + (long)(bm + m) * lda + k0 + qg * 8,
                    &As[(is * 256 + wv * 64) * 8]);
        }
        if constexpr (ACH % 256) {
            if (tid < ACH % 256) {
                int c = (ACH / 256) * 256 + tid;
                int m = c >> 2, kq = c & 3;
                int qg = kq ^ ((m >> 1) & 3);
                gload16(Ag + (long)(bm + m) * lda + k0 + qg * 8,
                        &As[((ACH / 256) * 256 + wv * 64) * 8]);
            }
        }
        #pragma unroll
        for (int is = 0; is < BCH / 256; ++is) {
            int c = is * 256 + wv * 64 + ln;
            int m = c >> 2, kq = c & 3;
            int qg = kq ^ ((m >> 1) & 3);
            gload16(Bg + (long)(bn + m) * ldb + k0 + qg * 8,
                    &Bs[(is * 256 + wv * 64) * 8]);
        }
        if constexpr (BCH % 256) {
            if (tid < BCH % 256) {
                int c = (BCH / 256) * 256 + tid;
                int m = c >> 2, kq = c & 3;
                int qg = kq ^ ((m >> 1) & 3);
                gload16(Bg + (long)(bn + m) * ldb + k0 + qg * 8,
                        &Bs[((BCH / 256) * 256 + wv * 64) * 8]);
            }
        }
        __syncthreads();
        s8v av[WM], bv[WN];
        #pragma unroll
        for (int i = 0; i < WM; ++i) {
            int row = wr * (WM * 16) + i * 16 + fr;
            av[i] = *(const s8v*)&As[row * 32 + (fq ^ ((row >> 1) & 3)) * 8];
        }
        #pragma unroll
        for (int j = 0; j < WN; ++j) {
            int row = wc * (WN * 16) + j * 16 + fr;
            bv[j] = *(const s8v*)&Bs[row * 32 + (fq ^ ((row >> 1) & 3)) * 8];
        }
        #pragma unroll
        for (int i = 0; i < WM; ++i)
            #pragma unroll
            for (int j = 0; j < WN; ++j)
                acc[i][j] = __builtin_amdgcn_mfma_f32_16x16x32_bf16(av[i], bv[j], acc[i][j], 0, 0, 0);
        __syncthreads();
    }

    #pragma unroll
    for (int i = 0; i < WM; ++i) {
        #pragma unroll
        for (int r = 0; r < 4; ++r) {
            int row = bm + wr * (WM * 16) + i * 16 + fq * 4 + r;
            if (GROUPED && row >= m_count) continue;
            #pragma unroll
            for (int j = 0; j < WN; ++j) {
                int col = bn + wc * (WN * 16) + j * 16 + fr;
                if (col < N) {
                    float v = acc[i][j][r] * alpha;
                    if (OUTMODE == 2) {
                        atomicAdd(&Cf[(long)row * ldc + col], v);
                    } else {
                        if (biasp) v += biasp[col];
                        if (GELU) v = 0.5f * v * (1.f + erff(v * 0.70710678118654752f));
                        if (resid) v += resid[(long)row * ldc + col];
                        if (OUTMODE == 1) Cb[(long)row * ldc + col] = __float2bfloat16(v);
                        else              Cf[(long)row * ldc + col] = v;
                    }
                }
            }
        }
    }
}

// Standalone wrapper (PV, out-proj)
template<int WM, int WN, bool GROUPED, bool GELU, int OUTMODE>
__global__ __launch_bounds__(256) void mfma_gemm(
    const bf16* A, const bf16* B, const float* bias, const float* resid,
    void* Cv, int M, int N, int K, int lda, int ldb, int ldc,
    int zdiv, int ksplit,
    long a_hi, long a_lo, long b_hi, long b_lo, long c_hi, long c_lo,
    long bias_stride, const int* grp_off, float alpha)
{
    __shared__ char smem[(32 * WM + 32 * WN) * 32 * 2];
    dev_mfma_gemm<WM, WN, GROUPED, GELU, OUTMODE>(
        A, B, bias, resid, Cv, M, N, K, lda, ldb, ldc, zdiv, ksplit,
        a_hi, a_lo, b_hi, b_lo, c_hi, c_lo, bias_stride, grp_off, alpha,
        blockIdx.x, blockIdx.y, blockIdx.z, smem);
}

// ---------------- weight transpose-convert tile (blocked output) -------------
__device__ __forceinline__ void dev_wtrans(int id,
                                           const float* __restrict__ w1,
                                           bf16* __restrict__ w1t,
                                           const float* __restrict__ w2,
                                           bf16* __restrict__ w2t,
                                           char* smem) {
    const float* in; bf16* out; int C, e, ct, rt;
    if (id < 4608) {                     // w1: 8 x (48 ct x 12 rt)
        e = id / 576; int rem = id % 576; ct = rem / 12; rt = rem % 12;
        in = w1; out = w1t; C = FFDIM;
    } else {
        id -= 4608;                      // w2: 8 x (12 ct x 48 rt)
        e = id / 576; int rem = id % 576; ct = rem / 48; rt = rem % 48;
        in = w2; out = w2t; C = DIM;
    }
    long ibase = (long)e * DIM * FFDIM;
    int rt0 = rt * 64, ct0 = ct * 64;
    float (*tile)[65] = (float(*)[65])smem;
    int t = threadIdx.x;
    {
        int q = t >> 4, cq = t & 15;
        #pragma unroll
        for (int i = 0; i < 4; ++i) {
            int row = q + i * 16;
            float4 v = *(const float4*)&in[ibase + (long)(rt0 + row) * C + ct0 + cq * 4];
            tile[row][cq * 4]     = v.x;
            tile[row][cq * 4 + 1] = v.y;
            tile[row][cq * 4 + 2] = v.z;
            tile[row][cq * 4 + 3] = v.w;
        }
    }
    __syncthreads();
    {
        int kb2 = t >> 6, n = t & 63;
        #pragma unroll
        for (int i = 0; i < 2; ++i) {
            int kblk = kb2 + 4 * i;
            unsigned w[4];
            #pragma unroll
            for (int j = 0; j < 4; ++j) {
                w[j] = ((unsigned)bf16bits(tile[kblk * 8 + 2 * j + 1][n]) << 16)
                     | bf16bits(tile[kblk * 8 + 2 * j][n]);
            }
            uint4 u; u.x = w[0]; u.y = w[1]; u.z = w[2]; u.w = w[3];
            *(uint4*)&out[ibase + ((long)(rt0 >> 3) + kblk) * C * 8 + (long)(ct0 + n) * 8] = u;
        }
    }
}

// ---------------- fused: qkv GEMM + w1 transpose (INTERLEAVED block map) ------
__global__ __launch_bounds__(256) void qkv_w1_kernel(
    const bf16* __restrict__ h_b, const bf16* __restrict__ in_wb,
    const float* __restrict__ in_b, bf16* __restrict__ qkv_b,
    const float* __restrict__ w1, bf16* __restrict__ w1t,
    const float* __restrict__ w2, bf16* __restrict__ w2t) {
    __shared__ char smem[16640];
    int bid = blockIdx.x;
    if (bid % 9 == 0) {
        int g = bid / 9;                               // 0..575
        dev_mfma_gemm<2, 2, false, false, 1>(
            h_b, in_wb, in_b, nullptr, qkv_b,
            NTOK, 3 * DIM, DIM, DIM, DIM, 3 * DIM,
            1, 1, 0, 0, 0, 0, 0, 0, 0, nullptr, 1.f,
            g % 36, g / 36, 0, smem);
    } else {
        int tr = bid - bid / 9 - 1;                    // 0..4607 = w1 ids
        dev_wtrans(tr, w1, w1t, w2, w2t, smem);
    }
}

// ---------------- fused: scores GEMM + w2 transpose (INTERLEAVED) -------------
__global__ __launch_bounds__(256) void scores_w2_kernel(
    const bf16* __restrict__ qkv_b, bf16* __restrict__ scores,
    const float* __restrict__ w1, bf16* __restrict__ w1t,
    const float* __restrict__ w2, bf16* __restrict__ w2t) {
    __shared__ char smem[16640];
    int bid = blockIdx.x;
    if (bid % 7 == 0) {
        int g = bid / 7;                               // 0..767
        dev_mfma_gemm<2, 4, false, false, 1>(
            qkv_b, qkv_b + DIM, nullptr, nullptr, scores,
            SEQ, SEQ, HDIM, 3 * DIM, 3 * DIM, SEQ,
            HEADS, 1, (long)SEQ * 3 * DIM, HDIM, (long)SEQ * 3 * DIM, HDIM,
            (long)HEADS * SEQ * SEQ, (long)SEQ * SEQ,
            0, nullptr, 0.125f,
            g % 4, (g >> 2) & 7, g >> 5, smem);
    } else {
        int tr = bid - bid / 7 - 1;                    // 0..4607 -> w2 ids
        dev_wtrans(4608 + tr, w1, w1t, w2, w2t, smem);
    }
}

// ---------------- MoE grouped GEMM v12: chunk-blocked B layout ----------------
template<int FM, int FN, int XT, int YCAP, int KS, bool GELU, int OUTMODE, bool GATHER>
__global__ __launch_bounds__(256) void moe_gemm(
    const bf16* __restrict__ A, const bf16* __restrict__ B,
    const float* __restrict__ bias, void* __restrict__ Cv,
    int lda, int Nt, int ldc, int Ktot, long b_hi, long bias_stride,
    const int* __restrict__ grp_off, const int* __restrict__ entry_tok,
    int N, long pstride)
{
    static_assert(OUTMODE != 1 || KS == 1, "plain bf16 store requires no split-K");
    constexpr int BM = FM * 32, BN = FN * 32;
    constexpr int GA = BM / 64;
    constexpr int GB = BN / 64;
    constexpr int G = GA + GB;

    int bid = blockIdx.x;
    int e = bid & 7;
    int r = bid >> 3;
    int xt = r % XT; r /= XT;
    int yt = r % YCAP;
    int ks = r / YCAP;
    int m0 = grp_off[e], m1 = grp_off[e + 1];
    int m_count = m1 - m0;
    int bm = yt * BM;
    if (bm >= m_count) return;
    int bn = xt * BN;
    int kper = Ktot / KS;

    const short* Ag = (const short*)A + (GATHER ? 0 : (long)m0 * lda);
    const short* Bg = (const short*)(B + (long)e * b_hi);
    const float* biasp = bias ? bias + (long)e * bias_stride : nullptr;
    float* Cf = (float*)Cv + (long)m0 * ldc + (long)ks * pstride;
    bf16*  Cb = (bf16*)Cv + (long)m0 * ldc;

    __shared__ short As[3][BM * 32];
    __shared__ short Bs[3][BN * 32];

    int tid = threadIdx.x;
    int wv = tid >> 6, ln = tid & 63;
    int wr = wv >> 1, wc = wv & 1;
    int fr = ln & 15, fq = ln >> 4;

    long arow[GA];
    #pragma unroll
    for (int is = 0; is < GA; ++is) {
        int c = is * 256 + wv * 64 + ln;
        int m = c >> 2;
        if (GATHER) {
            int gi = m0 + bm + m;
            arow[is] = (long)entry_tok[gi < NENT ? gi : NENT - 1] * lda;
        } else {
            arow[is] = (long)(bm + m) * lda;
        }
    }

    f4v acc[FM][FN] = {};

    auto stage = [&](int buf, int k0) {
        #pragma unroll
        for (int is = 0; is < GA; ++is) {
            int c = is * 256 + wv * 64 + ln;
            int m = c >> 2, q = c & 3;
            int qg = q ^ ((m >> 1) & 3);
            gload16(Ag + arow[is] + k0 + qg * 8,
                    &As[buf][(is * 256 + wv * 64) * 8]);
        }
        #pragma unroll
        for (int is = 0; is < GB; ++is) {
            int c = is * 256 + wv * 64 + ln;
            int n = c >> 2, q = c & 3;
            int qg = q ^ ((n >> 1) & 3);
            gload16(Bg + ((long)(k0 >> 3) + qg) * Nt * 8 + (long)(bn + n) * 8,
                    &Bs[buf][(is * 256 + wv * 64) * 8]);
        }
    };

    int kbeg = ks * kper;
    int nit = kper / 32;
    stage(0, kbeg);
    if (nit > 1) stage(1, kbeg + 32);

    for (int it = 0; it < nit; ++it) {
        if (it + 1 < nit) asm volatile("s_waitcnt vmcnt(%0)" :: "i"(G) : "memory");
        else              asm volatile("s_waitcnt vmcnt(0)" ::: "memory");
        __builtin_amdgcn_s_barrier();
        if (it + 2 < nit) stage((it + 2) % 3, kbeg + (it + 2) * 32);
        int cur = it % 3;
        __builtin_amdgcn_s_setprio(1);
        {
            s8v av[FM], bv[FN];
            #pragma unroll
            for (int i = 0; i < FM; ++i) {
                int row = wr * (FM * 16) + i * 16 + fr;
                av[i] = *(const s8v*)&As[cur][row * 32 + (fq ^ ((row >> 1) & 3)) * 8];
            }
            #pragma unroll
            for (int j = 0; j < FN; ++j) {
                int row = wc * (FN * 16) + j * 16 + fr;
                bv[j] = *(const s8v*)&Bs[cur][row * 32 + (fq ^ ((row >> 1) & 3)) * 8];
            }
            #pragma unroll
            for (int i = 0; i < FM; ++i)
                #pragma unroll
                for (int j = 0; j < FN; ++j)
                    acc[i][j] = __builtin_amdgcn_mfma_f32_16x16x32_bf16(av[i], bv[j], acc[i][j], 0, 0, 0);
        }
        __builtin_amdgcn_s_setprio(0);
    }

    #pragma unroll
    for (int i = 0; i < FM; ++i) {
        #pragma unroll
        for (int rr = 0; rr < 4; ++rr) {
            int row = bm + wr * (FM * 16) + i * 16 + fq * 4 + rr;
            if (row >= m_count) continue;
            #pragma unroll
            for (int j = 0; j < FN; ++j) {
                int col = bn + wc * (FN * 16) + j * 16 + fr;
                float v = acc[i][j][rr];
                if (OUTMODE == 0) {
                    Cf[(long)row * ldc + col] = v;
                } else {
                    if (biasp) v += biasp[col];
                    if (GELU) v = 0.5f * v * (1.f + erff(v * 0.70710678118654752f));
                    Cb[(long)row * ldc + col] = __float2bfloat16(v);
                }
            }
        }
    }
}

// ---------------- fused: softmax (3072 blocks) + V transpose (192 blocks) ----
__global__ __launch_bounds__(256) void softmax_vt_kernel(
    const bf16* __restrict__ s, bf16* __restrict__ attn,
    const bf16* __restrict__ qkvb, bf16* __restrict__ vt) {
    __shared__ short tile[64][65];
    int bid = blockIdx.x;
    int t = threadIdx.x;
    if (bid < 3072) {                    // softmax: wave per row
        long row = (long)bid * 4 + (t >> 6);
        int ln = t & 63;
        const unsigned* p = (const unsigned*)(s + row * 512);
        uint4 v = *(const uint4*)(p + ln * 4);
        unsigned u[4] = {v.x, v.y, v.z, v.w};
        float f[8];
        #pragma unroll
        for (int j = 0; j < 4; ++j) {
            f[2*j]   = bfbits2f(u[j] << 16);
            f[2*j+1] = bfbits2f(u[j] & 0xffff0000u);
        }
        float m = f[0];
        #pragma unroll
        for (int j = 1; j < 8; ++j) m = fmaxf(m, f[j]);
        #pragma unroll
        for (int o = 32; o; o >>= 1) m = fmaxf(m, __shfl_xor(m, o));
        float e[8], ssum = 0.f;
        #pragma unroll
        for (int j = 0; j < 8; ++j) { e[j] = expf(f[j] - m); ssum += e[j]; }
        #pragma unroll
        for (int o = 32; o; o >>= 1) ssum += __shfl_xor(ssum, o);
        float inv = 1.f / ssum;
        unsigned w[4];
        #pragma unroll
        for (int j = 0; j < 4; ++j) {
            bf16 lo = __float2bfloat16(e[2*j] * inv);
            bf16 hi = __float2bfloat16(e[2*j+1] * inv);
            w[j] = ((unsigned)*(unsigned short*)&hi << 16) | *(unsigned short*)&lo;
        }
        uint4 o4; o4.x = w[0]; o4.y = w[1]; o4.z = w[2]; o4.w = w[3];
        *(uint4*)((unsigned*)(attn + row * 512) + ln * 4) = o4;
    } else {                             // V transpose
        int id = bid - 3072;             // 0..191
        int st = id % 8;
        int z = id / 8;
        int b = z / HEADS, h = z % HEADS;
        int d = t & 63, s0 = t >> 6;
        const short* q = (const short*)qkvb;
        #pragma unroll
        for (int i = 0; i < 16; ++i) {
            int sq = st * 64 + s0 + i * 4;
            tile[s0 + i * 4][d] = q[(long)(b * SEQ + sq) * 2304 + 2 * DIM + h * HDIM + d];
        }
        __syncthreads();
        short* o = (short*)vt;
        #pragma unroll
        for (int i = 0; i < 16; ++i) {
            int d2 = (t >> 6) + i * 4;
            o[(long)(z * 64 + d2) * 512 + st * 64 + (t & 63)] = tile[t & 63][d2];
        }
    }
}

// ---------------- build per-expert entry lists (single block) ----------------
__global__ __launch_bounds__(1024) void build_lists(const int* __restrict__ e_sel,
                                                    int* __restrict__ entry_tok,
                                                    int* __restrict__ pos,
                                                    int* __restrict__ grp_off) {
    __shared__ int cnt[NEXP];
    __shared__ int off[NEXP + 1];
    __shared__ int cur[NEXP];
    int tid = threadIdx.x;
    if (tid < NEXP) cnt[tid] = 0;
    __syncthreads();
    for (int i = tid; i < NENT; i += 1024) atomicAdd(&cnt[e_sel[i]], 1);
    __syncthreads();
    if (tid == 0) {
        off[0] = 0;
        for (int e = 0; e < NEXP; ++e) off[e + 1] = off[e] + cnt[e];
        for (int e = 0; e < NEXP; ++e) cur[e] = off[e];
    }
    __syncthreads();
    for (int i = tid; i < NENT; i += 1024) {
        int e = e_sel[i];
        int p = atomicAdd(&cur[e], 1);
        entry_tok[p] = i >> 1;
        pos[i] = p;
    }
    if (tid < NEXP + 1) grp_off[tid] = off[tid];
}

// ---------------- final combine (float4): out = x1 + sum_s w_s*(b2+sum parts) -
__global__ __launch_bounds__(256) void combine_kernel(const float* __restrict__ x1,
                                                      const float* __restrict__ ypart,
                                                      const float* __restrict__ b2,
                                                      const int* __restrict__ pos,
                                                      const int* __restrict__ e_sel,
                                                      const float* __restrict__ wsel,
                                                      float* __restrict__ out) {
    long i4 = (long)blockIdx.x * 256 + threadIdx.x;      // float4 units; 196608 total
    if (i4 >= (long)NTOK * DIM / 4) return;
    int t = (int)(i4 / 192), d4 = (int)(i4 % 192);
    const float4* x1v = (const float4*)x1;
    const float4* ypv = (const float4*)ypart;
    const float4* b2v = (const float4*)b2;
    float4 v = x1v[i4];
    #pragma unroll
    for (int s = 0; s < 2; ++s) {
        long base = (long)pos[t * 2 + s] * 192 + d4;
        float4 y = b2v[(long)e_sel[t * 2 + s] * 192 + d4];
        #pragma unroll
        for (int ks = 0; ks < 4; ++ks) {
            float4 pp = ypv[base + ks * (YPS / 4)];
            y.x += pp.x; y.y += pp.y; y.z += pp.z; y.w += pp.w;
        }
        float w = wsel[t * 2 + s];
        v.x += w * y.x; v.y += w * y.y; v.z += w * y.z; v.w += w * y.w;
    }
    ((float4*)out)[i4] = v;
}

extern "C" void kernel_launch(void* const* d_in, const int* in_sizes, int n_in,
                              void* d_out, int out_size, void* d_ws, size_t ws_size,
                              hipStream_t stream) {
    const float* x        = (const float*)d_in[0];
    const float* ln1_g    = (const float*)d_in[1];
    const float* ln1_b    = (const float*)d_in[2];
    const float* ln2_g    = (const float*)d_in[3];
    const float* ln2_b    = (const float*)d_in[4];
    const float* in_w     = (const float*)d_in[5];
    const float* in_b     = (const float*)d_in[6];
    const float* out_w    = (const float*)d_in[7];
    const float* out_b    = (const float*)d_in[8];
    const float* router_w = (const float*)d_in[9];
    const float* router_b = (const float*)d_in[10];
    const float* w1       = (const float*)d_in[11];
    const float* b1       = (const float*)d_in[12];
    const float* w2       = (const float*)d_in[13];
    const float* b2       = (const float*)d_in[14];
    float* out = (float*)d_out;

    const long TD = (long)NTOK * DIM;
    char* p = (char*)d_ws;
    size_t off = 0;
    auto alloc = [&](size_t bytes) -> void* {
        void* r = p + off; off += (bytes + 255) & ~(size_t)255; return r;
    };
    bf16*  h_b    = (bf16*)alloc(TD * 2);
    bf16*  in_wb  = (bf16*)alloc(2304L * 768 * 2);
    bf16*  qkv_b  = (bf16*)alloc(1024L * 2304 * 2);
    bf16*  out_wb = (bf16*)alloc(768L * 768 * 2);
    bf16*  vt_b   = (bf16*)alloc((24L * 64 + 64) * 512 * 2);
    bf16*  oat_b  = (bf16*)alloc(TD * 2);
    float* opart  = (float*)alloc(2 * TD * 4);                 // out-proj K-partials
    float* x1     = (float*)alloc(TD * 4);
    bf16*  t2b    = (bf16*)alloc((NTOK + 256L) * DIM * 2);     // +pad (BM overread)
    bf16*  w1t    = (bf16*)alloc(8L * 3072 * 768 * 2);
    bf16*  w2t    = (bf16*)alloc(8L * 768 * 3072 * 2);
    bf16*  scores = (bf16*)alloc(24L * 512 * 512 * 2);
    bf16*  attn   = (bf16*)alloc(24L * 512 * 512 * 2);
    bf16*  hid    = (bf16*)alloc((2048L + 256) * 3072 * 2);    // +pad
    float* ypart  = (float*)alloc(4 * YPS * 4);                // 4 split-K partials
    int*   e_sel     = (int*)alloc(NENT * 4);
    float* w_sel     = (float*)alloc(NENT * 4);
    int*   entry_tok = (int*)alloc(NENT * 4);
    int*   pos       = (int*)alloc(NENT * 4);
    int*   grp_off   = (int*)alloc(64);

    // 1. FUSED: LN1 (1024 blocks, float4) + attention weight cvt (2304 blocks)
    ln1_cvt_kernel<<<NTOK + 2304, 256, 0, stream>>>(
        x, ln1_g, ln1_b, h_b,
        in_w, 2304L * 768, out_w, 768L * 768, in_wb, out_wb);
    // 2. FUSED+INTERLEAVED: qkv GEMM (576) + w1 transpose (4608)
    qkv_w1_kernel<<<576 + 4608, 256, 0, stream>>>(h_b, in_wb, in_b, qkv_b,
                                                  w1, w1t, w2, w2t);
    // 3. FUSED+INTERLEAVED: scores GEMM (768) + w2 transpose (4608)
    scores_w2_kernel<<<768 + 4608, 256, 0, stream>>>(qkv_b, scores,
                                                     w1, w1t, w2, w2t);
    // 4. FUSED: softmax (3072) + V transpose (192)
    softmax_vt_kernel<<<3072 + 192, 256, 0, stream>>>(scores, attn, qkv_b, vt_b);
    // 5. o = attn @ V -> oat bf16   BM=32: 384 blocks
    mfma_gemm<1, 2, false, false, 1><<<dim3(1, 16, 24), 256, 0, stream>>>(
        attn, vt_b, nullptr, nullptr, oat_b,
        SEQ, HDIM, SEQ, SEQ, SEQ, DIM,
        HEADS, 1, (long)HEADS * SEQ * SEQ, (long)SEQ * SEQ,
        (long)HEADS * HDIM * SEQ, (long)HDIM * SEQ,
        (long)SEQ * DIM, HDIM,
        0, nullptr, 1.f);
    // 6. out-proj split-K x2, plain partial stores
    mfma_gemm<2, 2, false, false, 0><<<dim3(12, 16, 2), 256, 0, stream>>>(
        oat_b, out_wb, nullptr, nullptr, opart,
        NTOK, DIM, 384, DIM, DIM, DIM,
        2, 1, 0, 384, 0, 384, 0, TD, 0, nullptr, 1.f);
    // 7. FUSED: LN2 + x1 assembly + router (float4; t2 f32 buffer eliminated)
    ln2x1r_kernel<<<NTOK, 256, 0, stream>>>(x, out_b, opart, ln2_g, ln2_b,
                                            router_w, router_b,
                                            x1, t2b, e_sel, w_sel);
    // 8. build lists
    build_lists<<<1, 1024, 0, stream>>>(e_sel, entry_tok, pos, grp_off);
    // 9. FFN1 grouped, GATHER-fused A: hid = gelu(t2b[tok] @ w1 + b1) -> bf16
    moe_gemm<4, 4, 24, 8, 1, true, 1, true><<<8 * 24 * 8, 256, 0, stream>>>(
        t2b, w1t, b1, hid,
        DIM, FFDIM, FFDIM, DIM, (long)FFDIM * DIM, FFDIM, grp_off, entry_tok,
        FFDIM, 0);
    // 10. FFN2 grouped split-K x4, plain partial stores
    moe_gemm<4, 4, 6, 8, 4, false, 0, false><<<8 * 6 * 8 * 4, 256, 0, stream>>>(
        hid, w2t, nullptr, ypart,
        FFDIM, DIM, DIM, FFDIM, (long)FFDIM * DIM, 0, grp_off, nullptr,
        DIM, YPS);
    // 11. combine (float4)
    combine_kernel<<<768, 256, 0, stream>>>(x1, ypart, b2, pos, e_sel, w_sel, out);
}

// Round 25
// 174.621 us; speedup vs baseline: 1.0684x; 1.0282x over previous
//
#include <hip/hip_runtime.h>
#include <hip/hip_bf16.h>

// Problem constants
#define BATCH 2
#define SEQ 512
#define DIM 768
#define HEADS 12
#define NEXP 8
#define FFDIM 3072
#define HDIM 64
#define NTOK (BATCH*SEQ)          // 1024
#define NENT (2*NTOK)             // 2048 (token, slot) entries
#define YPS ((long)NENT * DIM)    // partial-buffer stride (elements)

typedef __hip_bfloat16 bf16;
typedef __attribute__((ext_vector_type(8))) short s8v;
typedef __attribute__((ext_vector_type(4))) float f4v;

// ---- async global->LDS (16B per lane, wave-uniform LDS base + lane*16) ----
typedef __attribute__((address_space(1))) const unsigned char gas_u8;
typedef __attribute__((address_space(3))) unsigned char las_u8;
__device__ __forceinline__ void gload16(const void* g, void* l) {
    __builtin_amdgcn_global_load_lds((gas_u8*)g, (las_u8*)l, 16, 0, 0);
}

__device__ __forceinline__ float bfbits2f(unsigned hi16) {
    union { unsigned u; float f; } c; c.u = hi16; return c.f;
}
__device__ __forceinline__ unsigned short bf16bits(float f) {
    bf16 h = __float2bfloat16(f);
    return *reinterpret_cast<unsigned short*>(&h);
}
__device__ __forceinline__ uint2 pack4bf(float a, float b, float c, float d) {
    uint2 u;
    u.x = ((unsigned)bf16bits(b) << 16) | bf16bits(a);
    u.y = ((unsigned)bf16bits(d) << 16) | bf16bits(c);
    return u;
}

// ---------------- LN1 (vectorized) + weight cvt, fused ----------------
__global__ __launch_bounds__(256) void ln1_cvt_kernel(
    const float* __restrict__ x, const float* __restrict__ g,
    const float* __restrict__ b, bf16* __restrict__ outb,
    const float* __restrict__ wa, long na, const float* __restrict__ wb, long nb,
    bf16* __restrict__ oa, bf16* __restrict__ ob2) {
    int bid = blockIdx.x;
    int tid = threadIdx.x;
    if (bid >= NTOK) {                   // cvt part
        long i = ((long)(bid - NTOK) * 256 + tid) * 4;
        const float* src; bf16* dst; long idx;
        if (i < na) { src = wa; dst = oa; idx = i; }
        else if (i < na + nb) { src = wb; dst = ob2; idx = i - na; }
        else return;
        float4 v = *(const float4*)(src + idx);
        *(uint2*)(dst + idx) = pack4bf(v.x, v.y, v.z, v.w);
        return;
    }
    // LN1, float4 path: 192 active lanes
    long base4 = (long)bid * 192;
    float4 v = {0.f, 0.f, 0.f, 0.f};
    if (tid < 192) v = ((const float4*)x)[base4 + tid];
    float s = v.x + v.y + v.z + v.w;
    __shared__ float red[4];
    #pragma unroll
    for (int o = 32; o; o >>= 1) s += __shfl_xor(s, o);
    if ((tid & 63) == 0) red[tid >> 6] = s;
    __syncthreads();
    s = red[0] + red[1] + red[2] + red[3];
    float mu = s * (1.f / DIM);
    float4 d = {v.x - mu, v.y - mu, v.z - mu, v.w - mu};
    float q = (tid < 192) ? (d.x*d.x + d.y*d.y + d.z*d.z + d.w*d.w) : 0.f;
    __shared__ float red2[4];
    #pragma unroll
    for (int o = 32; o; o >>= 1) q += __shfl_xor(q, o);
    if ((tid & 63) == 0) red2[tid >> 6] = q;
    __syncthreads();
    q = red2[0] + red2[1] + red2[2] + red2[3];
    float rstd = rsqrtf(q * (1.f / DIM) + 1e-5f);
    if (tid < 192) {
        float4 g4 = ((const float4*)g)[tid];
        float4 b4 = ((const float4*)b)[tid];
        ((uint2*)outb)[base4 + tid] = pack4bf(
            d.x * rstd * g4.x + b4.x, d.y * rstd * g4.y + b4.y,
            d.z * rstd * g4.z + b4.z, d.w * rstd * g4.w + b4.w);
    }
}

// ---------------- LN2 + x1 assembly + ROUTER, fully fused ----------------
__global__ __launch_bounds__(256) void ln2x1r_kernel(
    const float* __restrict__ x, const float* __restrict__ out_b,
    const float* __restrict__ op, const float* __restrict__ g,
    const float* __restrict__ b, const float* __restrict__ rw,
    const float* __restrict__ rb, float* __restrict__ x1,
    bf16* __restrict__ t2b, int* __restrict__ e_sel,
    float* __restrict__ w_sel) {
    int t = blockIdx.x;
    int tid = threadIdx.x;
    const long TD4 = (long)NTOK * DIM / 4;
    long base4 = (long)t * 192;
    float4 v = {0.f, 0.f, 0.f, 0.f};
    if (tid < 192) {
        long i4 = base4 + tid;
        float4 xv = ((const float4*)x)[i4];
        float4 ob = ((const float4*)out_b)[tid];
        float4 o0 = ((const float4*)op)[i4];
        float4 o1 = ((const float4*)op)[i4 + TD4];
        v.x = xv.x + ob.x + o0.x + o1.x;
        v.y = xv.y + ob.y + o0.y + o1.y;
        v.z = xv.z + ob.z + o0.z + o1.z;
        v.w = xv.w + ob.w + o0.w + o1.w;
        ((float4*)x1)[i4] = v;
    }
    float s = v.x + v.y + v.z + v.w;
    __shared__ float red[4];
    #pragma unroll
    for (int o = 32; o; o >>= 1) s += __shfl_xor(s, o);
    if ((tid & 63) == 0) red[tid >> 6] = s;
    __syncthreads();
    s = red[0] + red[1] + red[2] + red[3];
    float mu = s * (1.f / DIM);
    float4 d = {v.x - mu, v.y - mu, v.z - mu, v.w - mu};
    float q = (tid < 192) ? (d.x*d.x + d.y*d.y + d.z*d.z + d.w*d.w) : 0.f;
    __shared__ float red2[4];
    #pragma unroll
    for (int o = 32; o; o >>= 1) q += __shfl_xor(q, o);
    if ((tid & 63) == 0) red2[tid >> 6] = q;
    __syncthreads();
    q = red2[0] + red2[1] + red2[2] + red2[3];
    float rstd = rsqrtf(q * (1.f / DIM) + 1e-5f);
    float4 ov = {0.f, 0.f, 0.f, 0.f};
    if (tid < 192) {
        float4 g4 = ((const float4*)g)[tid];
        float4 b4 = ((const float4*)b)[tid];
        ov.x = d.x * rstd * g4.x + b4.x;
        ov.y = d.y * rstd * g4.y + b4.y;
        ov.z = d.z * rstd * g4.z + b4.z;
        ov.w = d.w * rstd * g4.w + b4.w;
        ((uint2*)t2b)[base4 + tid] = pack4bf(ov.x, ov.y, ov.z, ov.w);
    }
    // Router: 8 logits via block-wide dot products with the in-register row.
    float part[NEXP];
    #pragma unroll
    for (int e = 0; e < NEXP; ++e) {
        float pv = 0.f;
        if (tid < 192) {
            float4 w4 = ((const float4*)rw)[(long)e * 192 + tid];
            pv = ov.x * w4.x + ov.y * w4.y + ov.z * w4.z + ov.w * w4.w;
        }
        part[e] = pv;
    }
    __shared__ float rred[4][NEXP];
    #pragma unroll
    for (int e = 0; e < NEXP; ++e) {
        float pv = part[e];
        #pragma unroll
        for (int o = 32; o; o >>= 1) pv += __shfl_xor(pv, o);
        if ((tid & 63) == 0) rred[tid >> 6][e] = pv;
    }
    __syncthreads();
    if (tid == 0) {
        float logits[NEXP];
        #pragma unroll
        for (int e = 0; e < NEXP; ++e)
            logits[e] = rred[0][e] + rred[1][e] + rred[2][e] + rred[3][e] + rb[e];
        int e0 = -1, e1 = -1;
        float l0 = -1e30f, l1 = -1e30f;
        #pragma unroll
        for (int e = 0; e < NEXP; ++e) {
            float l = logits[e];
            if (l > l0) { l1 = l0; e1 = e0; l0 = l; e0 = e; }
            else if (l > l1) { l1 = l; e1 = e; }
        }
        float p1 = expf(l1 - l0);
        float inv = 1.f / (1.f + p1);
        e_sel[t * 2] = e0;  e_sel[t * 2 + 1] = e1;
        w_sel[t * 2] = inv; w_sel[t * 2 + 1] = p1 * inv;
    }
}

// ---------------- MFMA GEMM device body (attention-side) ----------------
template<int WM, int WN, bool GROUPED, bool GELU, int OUTMODE>
__device__ __forceinline__ void dev_mfma_gemm(
    const bf16* __restrict__ A, const bf16* __restrict__ B,
    const float* __restrict__ bias, const float* __restrict__ resid,
    void* __restrict__ Cv,
    int M, int N, int K, int lda, int ldb, int ldc,
    int zdiv, int ksplit,
    long a_hi, long a_lo, long b_hi, long b_lo, long c_hi, long c_lo,
    long bias_stride, const int* __restrict__ grp_off, float alpha,
    int bx, int by, int bz, char* smem)
{
    constexpr int BM = 32 * WM, BN = 32 * WN;
    constexpr int ACH = BM * 4;     // 16B chunks in A tile
    constexpr int BCH = BN * 4;

    int z = bz;
    int ze = z / ksplit, ks = z % ksplit;
    int kper = K / ksplit;
    long aoff, boff, coff;
    int m_count = M;
    if (GROUPED) {
        int m0 = grp_off[ze], m1 = grp_off[ze + 1];
        m_count = m1 - m0;
        if (by * BM >= m_count) return;
        aoff = (long)m0 * lda;
        coff = (long)m0 * ldc;
        boff = (long)ze * b_hi;
    } else {
        int zh = ze / zdiv, zl = ze % zdiv;
        aoff = zh * a_hi + zl * a_lo;
        boff = zh * b_hi + zl * b_lo;
        coff = zh * c_hi + zl * c_lo;
    }
    const short* Ag = (const short*)(A + aoff);
    const short* Bg = (const short*)(B + boff);
    const float* biasp = bias ? bias + (long)ze * bias_stride : nullptr;
    float* Cf = (float*)Cv + coff;
    bf16*  Cb = (bf16*)Cv + coff;

    short* As = (short*)smem;
    short* Bs = As + BM * 32;

    int tid = threadIdx.x;
    int wv = tid >> 6, ln = tid & 63;
    int wr = wv >> 1, wc = wv & 1;
    int fr = ln & 15, fq = ln >> 4;
    int bm = by * BM, bn = bx * BN;

    f4v acc[WM][WN] = {};

    for (int k0 = ks * kper; k0 < (ks + 1) * kper; k0 += 32) {
        #pragma unroll
        for (int is = 0; is < ACH / 256; ++is) {
            int c = is * 256 + wv * 64 + ln;
            int m = c >> 2, kq = c & 3;
            int qg = kq ^ ((m >> 1) & 3);
            gload16(Ag + (long)(bm + m) * lda + k0 + qg * 8,
                    &As[(is * 256 + wv * 64) * 8]);
        }
        if constexpr (ACH % 256) {
            if (tid < ACH % 256) {
                int c = (ACH / 256) * 256 + tid;
                int m = c >> 2, kq = c & 3;
                int qg = kq ^ ((m >> 1) & 3);
                gload16(Ag + (long)(bm + m) * lda + k0 + qg * 8,
                        &As[((ACH / 256) * 256 + wv * 64) * 8]);
            }
        }
        #pragma unroll
        for (int is = 0; is < BCH / 256; ++is) {
            int c = is * 256 + wv * 64 + ln;
            int m = c >> 2, kq = c & 3;
            int qg = kq ^ ((m >> 1) & 3);
            gload16(Bg + (long)(bn + m) * ldb + k0 + qg * 8,
                    &Bs[(is * 256 + wv * 64) * 8]);
        }
        if constexpr (BCH % 256) {
            if (tid < BCH % 256) {
                int c = (BCH / 256) * 256 + tid;
                int m = c >> 2, kq = c & 3;
                int qg = kq ^ ((m >> 1) & 3);
                gload16(Bg + (long)(bn + m) * ldb + k0 + qg * 8,
                        &Bs[((BCH / 256) * 256 + wv * 64) * 8]);
            }
        }
        __syncthreads();
        s8v av[WM], bv[WN];
        #pragma unroll
        for (int i = 0; i < WM; ++i) {
            int row = wr * (WM * 16) + i * 16 + fr;
            av[i] = *(const s8v*)&As[row * 32 + (fq ^ ((row >> 1) & 3)) * 8];
        }
        #pragma unroll
        for (int j = 0; j < WN; ++j) {
            int row = wc * (WN * 16) + j * 16 + fr;
            bv[j] = *(const s8v*)&Bs[row * 32 + (fq ^ ((row >> 1) & 3)) * 8];
        }
        #pragma unroll
        for (int i = 0; i < WM; ++i)
            #pragma unroll
            for (int j = 0; j < WN; ++j)
                acc[i][j] = __builtin_amdgcn_mfma_f32_16x16x32_bf16(av[i], bv[j], acc[i][j], 0, 0, 0);
        __syncthreads();
    }

    #pragma unroll
    for (int i = 0; i < WM; ++i) {
        #pragma unroll
        for (int r = 0; r < 4; ++r) {
            int row = bm + wr * (WM * 16) + i * 16 + fq * 4 + r;
            if (GROUPED && row >= m_count) continue;
            #pragma unroll
            for (int j = 0; j < WN; ++j) {
                int col = bn + wc * (WN * 16) + j * 16 + fr;
                if (col < N) {
                    float v = acc[i][j][r] * alpha;
                    if (OUTMODE == 2) {
                        atomicAdd(&Cf[(long)row * ldc + col], v);
                    } else {
                        if (biasp) v += biasp[col];
                        if (GELU) v = 0.5f * v * (1.f + erff(v * 0.70710678118654752f));
                        if (resid) v += resid[(long)row * ldc + col];
                        if (OUTMODE == 1) Cb[(long)row * ldc + col] = __float2bfloat16(v);
                        else              Cf[(long)row * ldc + col] = v;
                    }
                }
            }
        }
    }
}

// Standalone wrapper (PV, out-proj)
template<int WM, int WN, bool GROUPED, bool GELU, int OUTMODE>
__global__ __launch_bounds__(256) void mfma_gemm(
    const bf16* A, const bf16* B, const float* bias, const float* resid,
    void* Cv, int M, int N, int K, int lda, int ldb, int ldc,
    int zdiv, int ksplit,
    long a_hi, long a_lo, long b_hi, long b_lo, long c_hi, long c_lo,
    long bias_stride, const int* grp_off, float alpha)
{
    __shared__ char smem[(32 * WM + 32 * WN) * 32 * 2];
    dev_mfma_gemm<WM, WN, GROUPED, GELU, OUTMODE>(
        A, B, bias, resid, Cv, M, N, K, lda, ldb, ldc, zdiv, ksplit,
        a_hi, a_lo, b_hi, b_lo, c_hi, c_lo, bias_stride, grp_off, alpha,
        blockIdx.x, blockIdx.y, blockIdx.z, smem);
}

// ---------------- weight transpose-convert tile (blocked output) -------------
__device__ __forceinline__ void dev_wtrans(int id,
                                           const float* __restrict__ w1,
                                           bf16* __restrict__ w1t,
                                           const float* __restrict__ w2,
                                           bf16* __restrict__ w2t,
                                           char* smem) {
    const float* in; bf16* out; int C, e, ct, rt;
    if (id < 4608) {                     // w1: 8 x (48 ct x 12 rt)
        e = id / 576; int rem = id % 576; ct = rem / 12; rt = rem % 12;
        in = w1; out = w1t; C = FFDIM;
    } else {
        id -= 4608;                      // w2: 8 x (12 ct x 48 rt)
        e = id / 576; int rem = id % 576; ct = rem / 48; rt = rem % 48;
        in = w2; out = w2t; C = DIM;
    }
    long ibase = (long)e * DIM * FFDIM;
    int rt0 = rt * 64, ct0 = ct * 64;
    float (*tile)[65] = (float(*)[65])smem;
    int t = threadIdx.x;
    {
        int q = t >> 4, cq = t & 15;
        #pragma unroll
        for (int i = 0; i < 4; ++i) {
            int row = q + i * 16;
            float4 v = *(const float4*)&in[ibase + (long)(rt0 + row) * C + ct0 + cq * 4];
            tile[row][cq * 4]     = v.x;
            tile[row][cq * 4 + 1] = v.y;
            tile[row][cq * 4 + 2] = v.z;
            tile[row][cq * 4 + 3] = v.w;
        }
    }
    __syncthreads();
    {
        int kb2 = t >> 6, n = t & 63;
        #pragma unroll
        for (int i = 0; i < 2; ++i) {
            int kblk = kb2 + 4 * i;
            unsigned w[4];
            #pragma unroll
            for (int j = 0; j < 4; ++j) {
                w[j] = ((unsigned)bf16bits(tile[kblk * 8 + 2 * j + 1][n]) << 16)
                     | bf16bits(tile[kblk * 8 + 2 * j][n]);
            }
            uint4 u; u.x = w[0]; u.y = w[1]; u.z = w[2]; u.w = w[3];
            *(uint4*)&out[ibase + ((long)(rt0 >> 3) + kblk) * C * 8 + (long)(ct0 + n) * 8] = u;
        }
    }
}

// ---------------- fused: qkv GEMM + w1 transpose (INTERLEAVED block map) ------
__global__ __launch_bounds__(256) void qkv_w1_kernel(
    const bf16* __restrict__ h_b, const bf16* __restrict__ in_wb,
    const float* __restrict__ in_b, bf16* __restrict__ qkv_b,
    const float* __restrict__ w1, bf16* __restrict__ w1t,
    const float* __restrict__ w2, bf16* __restrict__ w2t) {
    __shared__ char smem[16640];
    int bid = blockIdx.x;
    if (bid % 9 == 0) {
        int g = bid / 9;                               // 0..575
        dev_mfma_gemm<2, 2, false, false, 1>(
            h_b, in_wb, in_b, nullptr, qkv_b,
            NTOK, 3 * DIM, DIM, DIM, DIM, 3 * DIM,
            1, 1, 0, 0, 0, 0, 0, 0, 0, nullptr, 1.f,
            g % 36, g / 36, 0, smem);
    } else {
        int tr = bid - bid / 9 - 1;                    // 0..4607 = w1 ids
        dev_wtrans(tr, w1, w1t, w2, w2t, smem);
    }
}

// ---------------- fused: scores GEMM + w2 transpose (INTERLEAVED) -------------
__global__ __launch_bounds__(256) void scores_w2_kernel(
    const bf16* __restrict__ qkv_b, bf16* __restrict__ scores,
    const float* __restrict__ w1, bf16* __restrict__ w1t,
    const float* __restrict__ w2, bf16* __restrict__ w2t) {
    __shared__ char smem[16640];
    int bid = blockIdx.x;
    if (bid % 7 == 0) {
        int g = bid / 7;                               // 0..767
        dev_mfma_gemm<2, 4, false, false, 1>(
            qkv_b, qkv_b + DIM, nullptr, nullptr, scores,
            SEQ, SEQ, HDIM, 3 * DIM, 3 * DIM, SEQ,
            HEADS, 1, (long)SEQ * 3 * DIM, HDIM, (long)SEQ * 3 * DIM, HDIM,
            (long)HEADS * SEQ * SEQ, (long)SEQ * SEQ,
            0, nullptr, 0.125f,
            g % 4, (g >> 2) & 7, g >> 5, smem);
    } else {
        int tr = bid - bid / 7 - 1;                    // 0..4607 -> w2 ids
        dev_wtrans(4608 + tr, w1, w1t, w2, w2t, smem);
    }
}

// ---------------- MoE grouped GEMM v13: chunk-blocked B, bf16 partials -------
// OUTMODE: 0 = f32 store at ks*pstride; 1 = bf16 store (+bias,+GELU), KS==1;
//          3 = bf16 store at ks*pstride (split-K partials, no bias).
template<int FM, int FN, int XT, int YCAP, int KS, bool GELU, int OUTMODE, bool GATHER>
__global__ __launch_bounds__(256) void moe_gemm(
    const bf16* __restrict__ A, const bf16* __restrict__ B,
    const float* __restrict__ bias, void* __restrict__ Cv,
    int lda, int Nt, int ldc, int Ktot, long b_hi, long bias_stride,
    const int* __restrict__ grp_off, const int* __restrict__ entry_tok,
    int N, long pstride)
{
    static_assert(OUTMODE != 1 || KS == 1, "plain bf16 store requires no split-K");
    constexpr int BM = FM * 32, BN = FN * 32;
    constexpr int GA = BM / 64;
    constexpr int GB = BN / 64;
    constexpr int G = GA + GB;

    int bid = blockIdx.x;
    int e = bid & 7;
    int r = bid >> 3;
    int xt = r % XT; r /= XT;
    int yt = r % YCAP;
    int ks = r / YCAP;
    int m0 = grp_off[e], m1 = grp_off[e + 1];
    int m_count = m1 - m0;
    int bm = yt * BM;
    if (bm >= m_count) return;
    int bn = xt * BN;
    int kper = Ktot / KS;

    const short* Ag = (const short*)A + (GATHER ? 0 : (long)m0 * lda);
    const short* Bg = (const short*)(B + (long)e * b_hi);
    const float* biasp = bias ? bias + (long)e * bias_stride : nullptr;
    float* Cf = (float*)Cv + (long)m0 * ldc + (long)ks * pstride;
    bf16*  Cb = (bf16*)Cv + (long)m0 * ldc + (long)ks * pstride;

    __shared__ short As[3][BM * 32];
    __shared__ short Bs[3][BN * 32];

    int tid = threadIdx.x;
    int wv = tid >> 6, ln = tid & 63;
    int wr = wv >> 1, wc = wv & 1;
    int fr = ln & 15, fq = ln >> 4;

    long arow[GA];
    #pragma unroll
    for (int is = 0; is < GA; ++is) {
        int c = is * 256 + wv * 64 + ln;
        int m = c >> 2;
        if (GATHER) {
            int gi = m0 + bm + m;
            arow[is] = (long)entry_tok[gi < NENT ? gi : NENT - 1] * lda;
        } else {
            arow[is] = (long)(bm + m) * lda;
        }
    }

    f4v acc[FM][FN] = {};

    auto stage = [&](int buf, int k0) {
        #pragma unroll
        for (int is = 0; is < GA; ++is) {
            int c = is * 256 + wv * 64 + ln;
            int m = c >> 2, q = c & 3;
            int qg = q ^ ((m >> 1) & 3);
            gload16(Ag + arow[is] + k0 + qg * 8,
                    &As[buf][(is * 256 + wv * 64) * 8]);
        }
        #pragma unroll
        for (int is = 0; is < GB; ++is) {
            int c = is * 256 + wv * 64 + ln;
            int n = c >> 2, q = c & 3;
            int qg = q ^ ((n >> 1) & 3);
            gload16(Bg + ((long)(k0 >> 3) + qg) * Nt * 8 + (long)(bn + n) * 8,
                    &Bs[buf][(is * 256 + wv * 64) * 8]);
        }
    };

    int kbeg = ks * kper;
    int nit = kper / 32;
    stage(0, kbeg);
    if (nit > 1) stage(1, kbeg + 32);

    for (int it = 0; it < nit; ++it) {
        if (it + 1 < nit) asm volatile("s_waitcnt vmcnt(%0)" :: "i"(G) : "memory");
        else              asm volatile("s_waitcnt vmcnt(0)" ::: "memory");
        __builtin_amdgcn_s_barrier();
        if (it + 2 < nit) stage((it + 2) % 3, kbeg + (it + 2) * 32);
        int cur = it % 3;
        __builtin_amdgcn_s_setprio(1);
        {
            s8v av[FM], bv[FN];
            #pragma unroll
            for (int i = 0; i < FM; ++i) {
                int row = wr * (FM * 16) + i * 16 + fr;
                av[i] = *(const s8v*)&As[cur][row * 32 + (fq ^ ((row >> 1) & 3)) * 8];
            }
            #pragma unroll
            for (int j = 0; j < FN; ++j) {
                int row = wc * (FN * 16) + j * 16 + fr;
                bv[j] = *(const s8v*)&Bs[cur][row * 32 + (fq ^ ((row >> 1) & 3)) * 8];
            }
            #pragma unroll
            for (int i = 0; i < FM; ++i)
                #pragma unroll
                for (int j = 0; j < FN; ++j)
                    acc[i][j] = __builtin_amdgcn_mfma_f32_16x16x32_bf16(av[i], bv[j], acc[i][j], 0, 0, 0);
        }
        __builtin_amdgcn_s_setprio(0);
    }

    #pragma unroll
    for (int i = 0; i < FM; ++i) {
        #pragma unroll
        for (int rr = 0; rr < 4; ++rr) {
            int row = bm + wr * (FM * 16) + i * 16 + fq * 4 + rr;
            if (row >= m_count) continue;
            #pragma unroll
            for (int j = 0; j < FN; ++j) {
                int col = bn + wc * (FN * 16) + j * 16 + fr;
                float v = acc[i][j][rr];
                if (OUTMODE == 0) {
                    Cf[(long)row * ldc + col] = v;
                } else if (OUTMODE == 3) {
                    Cb[(long)row * ldc + col] = __float2bfloat16(v);
                } else {
                    if (biasp) v += biasp[col];
                    if (GELU) v = 0.5f * v * (1.f + erff(v * 0.70710678118654752f));
                    Cb[(long)row * ldc + col] = __float2bfloat16(v);
                }
            }
        }
    }
}

// ---------------- fused: softmax (3072 blocks) + V transpose (192 blocks) ----
__global__ __launch_bounds__(256) void softmax_vt_kernel(
    const bf16* __restrict__ s, bf16* __restrict__ attn,
    const bf16* __restrict__ qkvb, bf16* __restrict__ vt) {
    __shared__ short tile[64][65];
    int bid = blockIdx.x;
    int t = threadIdx.x;
    if (bid < 3072) {                    // softmax: wave per row
        long row = (long)bid * 4 + (t >> 6);
        int ln = t & 63;
        const unsigned* p = (const unsigned*)(s + row * 512);
        uint4 v = *(const uint4*)(p + ln * 4);
        unsigned u[4] = {v.x, v.y, v.z, v.w};
        float f[8];
        #pragma unroll
        for (int j = 0; j < 4; ++j) {
            f[2*j]   = bfbits2f(u[j] << 16);
            f[2*j+1] = bfbits2f(u[j] & 0xffff0000u);
        }
        float m = f[0];
        #pragma unroll
        for (int j = 1; j < 8; ++j) m = fmaxf(m, f[j]);
        #pragma unroll
        for (int o = 32; o; o >>= 1) m = fmaxf(m, __shfl_xor(m, o));
        float e[8], ssum = 0.f;
        #pragma unroll
        for (int j = 0; j < 8; ++j) { e[j] = expf(f[j] - m); ssum += e[j]; }
        #pragma unroll
        for (int o = 32; o; o >>= 1) ssum += __shfl_xor(ssum, o);
        float inv = 1.f / ssum;
        unsigned w[4];
        #pragma unroll
        for (int j = 0; j < 4; ++j) {
            bf16 lo = __float2bfloat16(e[2*j] * inv);
            bf16 hi = __float2bfloat16(e[2*j+1] * inv);
            w[j] = ((unsigned)*(unsigned short*)&hi << 16) | *(unsigned short*)&lo;
        }
        uint4 o4; o4.x = w[0]; o4.y = w[1]; o4.z = w[2]; o4.w = w[3];
        *(uint4*)((unsigned*)(attn + row * 512) + ln * 4) = o4;
    } else {                             // V transpose
        int id = bid - 3072;             // 0..191
        int st = id % 8;
        int z = id / 8;
        int b = z / HEADS, h = z % HEADS;
        int d = t & 63, s0 = t >> 6;
        const short* q = (const short*)qkvb;
        #pragma unroll
        for (int i = 0; i < 16; ++i) {
            int sq = st * 64 + s0 + i * 4;
            tile[s0 + i * 4][d] = q[(long)(b * SEQ + sq) * 2304 + 2 * DIM + h * HDIM + d];
        }
        __syncthreads();
        short* o = (short*)vt;
        #pragma unroll
        for (int i = 0; i < 16; ++i) {
            int d2 = (t >> 6) + i * 4;
            o[(long)(z * 64 + d2) * 512 + st * 64 + (t & 63)] = tile[t & 63][d2];
        }
    }
}

// ---------------- build per-expert entry lists (single block) ----------------
__global__ __launch_bounds__(1024) void build_lists(const int* __restrict__ e_sel,
                                                    int* __restrict__ entry_tok,
                                                    int* __restrict__ pos,
                                                    int* __restrict__ grp_off) {
    __shared__ int cnt[NEXP];
    __shared__ int off[NEXP + 1];
    __shared__ int cur[NEXP];
    int tid = threadIdx.x;
    if (tid < NEXP) cnt[tid] = 0;
    __syncthreads();
    for (int i = tid; i < NENT; i += 1024) atomicAdd(&cnt[e_sel[i]], 1);
    __syncthreads();
    if (tid == 0) {
        off[0] = 0;
        for (int e = 0; e < NEXP; ++e) off[e + 1] = off[e] + cnt[e];
        for (int e = 0; e < NEXP; ++e) cur[e] = off[e];
    }
    __syncthreads();
    for (int i = tid; i < NENT; i += 1024) {
        int e = e_sel[i];
        int p = atomicAdd(&cur[e], 1);
        entry_tok[p] = i >> 1;
        pos[i] = p;
    }
    if (tid < NEXP + 1) grp_off[tid] = off[tid];
}

// ---------------- final combine (float4 out, bf16 partials) ------------------
// out = x1 + sum_s w_s*(b2[e_s] + sum_ks ypart_bf16)
__global__ __launch_bounds__(256) void combine_kernel(const float* __restrict__ x1,
                                                      const bf16* __restrict__ ypart,
                                                      const float* __restrict__ b2,
                                                      const int* __restrict__ pos,
                                                      const int* __restrict__ e_sel,
                                                      const float* __restrict__ wsel,
                                                      float* __restrict__ out) {
    long i4 = (long)blockIdx.x * 256 + threadIdx.x;      // 4-elem units; 196608 total
    if (i4 >= (long)NTOK * DIM / 4) return;
    int t = (int)(i4 / 192), d4 = (int)(i4 % 192);
    const float4* x1v = (const float4*)x1;
    const uint2* ypv = (const uint2*)ypart;              // 4 bf16 per uint2
    const float4* b2v = (const float4*)b2;
    float4 v = x1v[i4];
    #pragma unroll
    for (int s = 0; s < 2; ++s) {
        long base = (long)pos[t * 2 + s] * 192 + d4;
        float4 y = b2v[(long)e_sel[t * 2 + s] * 192 + d4];
        #pragma unroll
        for (int ks = 0; ks < 4; ++ks) {
            uint2 pp = ypv[base + ks * (YPS / 4)];
            y.x += bfbits2f(pp.x << 16);
            y.y += bfbits2f(pp.x & 0xffff0000u);
            y.z += bfbits2f(pp.y << 16);
            y.w += bfbits2f(pp.y & 0xffff0000u);
        }
        float w = wsel[t * 2 + s];
        v.x += w * y.x; v.y += w * y.y; v.z += w * y.z; v.w += w * y.w;
    }
    ((float4*)out)[i4] = v;
}

extern "C" void kernel_launch(void* const* d_in, const int* in_sizes, int n_in,
                              void* d_out, int out_size, void* d_ws, size_t ws_size,
                              hipStream_t stream) {
    const float* x        = (const float*)d_in[0];
    const float* ln1_g    = (const float*)d_in[1];
    const float* ln1_b    = (const float*)d_in[2];
    const float* ln2_g    = (const float*)d_in[3];
    const float* ln2_b    = (const float*)d_in[4];
    const float* in_w     = (const float*)d_in[5];
    const float* in_b     = (const float*)d_in[6];
    const float* out_w    = (const float*)d_in[7];
    const float* out_b    = (const float*)d_in[8];
    const float* router_w = (const float*)d_in[9];
    const float* router_b = (const float*)d_in[10];
    const float* w1       = (const float*)d_in[11];
    const float* b1       = (const float*)d_in[12];
    const float* w2       = (const float*)d_in[13];
    const float* b2       = (const float*)d_in[14];
    float* out = (float*)d_out;

    const long TD = (long)NTOK * DIM;
    char* p = (char*)d_ws;
    size_t off = 0;
    auto alloc = [&](size_t bytes) -> void* {
        void* r = p + off; off += (bytes + 255) & ~(size_t)255; return r;
    };
    bf16*  h_b    = (bf16*)alloc(TD * 2);
    bf16*  in_wb  = (bf16*)alloc(2304L * 768 * 2);
    bf16*  qkv_b  = (bf16*)alloc(1024L * 2304 * 2);
    bf16*  out_wb = (bf16*)alloc(768L * 768 * 2);
    bf16*  vt_b   = (bf16*)alloc((24L * 64 + 64) * 512 * 2);
    bf16*  oat_b  = (bf16*)alloc(TD * 2);
    float* opart  = (float*)alloc(2 * TD * 4);                 // out-proj K-partials
    float* x1     = (float*)alloc(TD * 4);
    bf16*  t2b    = (bf16*)alloc((NTOK + 256L) * DIM * 2);     // +pad (BM overread)
    bf16*  w1t    = (bf16*)alloc(8L * 3072 * 768 * 2);
    bf16*  w2t    = (bf16*)alloc(8L * 768 * 3072 * 2);
    bf16*  scores = (bf16*)alloc(24L * 512 * 512 * 2);
    bf16*  attn   = (bf16*)alloc(24L * 512 * 512 * 2);
    bf16*  hid    = (bf16*)alloc((2048L + 256) * 3072 * 2);    // +pad
    bf16*  ypart  = (bf16*)alloc(4 * YPS * 2);                 // 4 split-K bf16 partials
    int*   e_sel     = (int*)alloc(NENT * 4);
    float* w_sel     = (float*)alloc(NENT * 4);
    int*   entry_tok = (int*)alloc(NENT * 4);
    int*   pos       = (int*)alloc(NENT * 4);
    int*   grp_off   = (int*)alloc(64);

    // 1. FUSED: LN1 (1024 blocks, float4) + attention weight cvt (2304 blocks)
    ln1_cvt_kernel<<<NTOK + 2304, 256, 0, stream>>>(
        x, ln1_g, ln1_b, h_b,
        in_w, 2304L * 768, out_w, 768L * 768, in_wb, out_wb);
    // 2. FUSED+INTERLEAVED: qkv GEMM (576) + w1 transpose (4608)
    qkv_w1_kernel<<<576 + 4608, 256, 0, stream>>>(h_b, in_wb, in_b, qkv_b,
                                                  w1, w1t, w2, w2t);
    // 3. FUSED+INTERLEAVED: scores GEMM (768) + w2 transpose (4608)
    scores_w2_kernel<<<768 + 4608, 256, 0, stream>>>(qkv_b, scores,
                                                     w1, w1t, w2, w2t);
    // 4. FUSED: softmax (3072) + V transpose (192)
    softmax_vt_kernel<<<3072 + 192, 256, 0, stream>>>(scores, attn, qkv_b, vt_b);
    // 5. o = attn @ V -> oat bf16   BM=32: 384 blocks
    mfma_gemm<1, 2, false, false, 1><<<dim3(1, 16, 24), 256, 0, stream>>>(
        attn, vt_b, nullptr, nullptr, oat_b,
        SEQ, HDIM, SEQ, SEQ, SEQ, DIM,
        HEADS, 1, (long)HEADS * SEQ * SEQ, (long)SEQ * SEQ,
        (long)HEADS * HDIM * SEQ, (long)HDIM * SEQ,
        (long)SEQ * DIM, HDIM,
        0, nullptr, 1.f);
    // 6. out-proj split-K x2, plain partial stores
    mfma_gemm<2, 2, false, false, 0><<<dim3(12, 16, 2), 256, 0, stream>>>(
        oat_b, out_wb, nullptr, nullptr, opart,
        NTOK, DIM, 384, DIM, DIM, DIM,
        2, 1, 0, 384, 0, 384, 0, TD, 0, nullptr, 1.f);
    // 7. FUSED: LN2 + x1 assembly + router (float4)
    ln2x1r_kernel<<<NTOK, 256, 0, stream>>>(x, out_b, opart, ln2_g, ln2_b,
                                            router_w, router_b,
                                            x1, t2b, e_sel, w_sel);
    // 8. build lists
    build_lists<<<1, 1024, 0, stream>>>(e_sel, entry_tok, pos, grp_off);
    // 9. FFN1 grouped, GATHER-fused A: hid = gelu(t2b[tok] @ w1 + b1) -> bf16
    moe_gemm<4, 4, 24, 8, 1, true, 1, true><<<8 * 24 * 8, 256, 0, stream>>>(
        t2b, w1t, b1, hid,
        DIM, FFDIM, FFDIM, DIM, (long)FFDIM * DIM, FFDIM, grp_off, entry_tok,
        FFDIM, 0);
    // 10. FFN2 grouped split-K x4, bf16 partial stores (halved traffic)
    moe_gemm<4, 4, 6, 8, 4, false, 3, false><<<8 * 6 * 8 * 4, 256, 0, stream>>>(
        hid, w2t, nullptr, ypart,
        FFDIM, DIM, DIM, FFDIM, (long)FFDIM * DIM, 0, grp_off, nullptr,
        DIM, YPS);
    // 11. combine (float4 out, bf16 partials)
    combine_kernel<<<768, 256, 0, stream>>>(x1, ypart, b2, pos, e_sel, w_sel, out);
}

// Round 27
// 173.691 us; speedup vs baseline: 1.0741x; 1.0054x over previous
//
#include <hip/hip_runtime.h>
#include <hip/hip_bf16.h>

// Problem constants
#define BATCH 2
#define SEQ 512
#define DIM 768
#define HEADS 12
#define NEXP 8
#define FFDIM 3072
#define HDIM 64
#define NTOK (BATCH*SEQ)          // 1024
#define NENT (2*NTOK)             // 2048 (token, slot) entries
#define YPS ((long)NENT * DIM)    // partial-buffer stride (elements)

typedef __hip_bfloat16 bf16;
typedef __attribute__((ext_vector_type(8))) short s8v;
typedef __attribute__((ext_vector_type(4))) float f4v;

// ---- async global->LDS (16B per lane, wave-uniform LDS base + lane*16) ----
typedef __attribute__((address_space(1))) const unsigned char gas_u8;
typedef __attribute__((address_space(3))) unsigned char las_u8;
__device__ __forceinline__ void gload16(const void* g, void* l) {
    __builtin_amdgcn_global_load_lds((gas_u8*)g, (las_u8*)l, 16, 0, 0);
}

__device__ __forceinline__ float bfbits2f(unsigned hi16) {
    union { unsigned u; float f; } c; c.u = hi16; return c.f;
}
__device__ __forceinline__ unsigned short bf16bits(float f) {
    bf16 h = __float2bfloat16(f);
    return *reinterpret_cast<unsigned short*>(&h);
}
__device__ __forceinline__ uint2 pack4bf(float a, float b, float c, float d) {
    uint2 u;
    u.x = ((unsigned)bf16bits(b) << 16) | bf16bits(a);
    u.y = ((unsigned)bf16bits(d) << 16) | bf16bits(c);
    return u;
}

// ---------------- LN1 (vectorized) + weight cvt, fused ----------------
__global__ __launch_bounds__(256) void ln1_cvt_kernel(
    const float* __restrict__ x, const float* __restrict__ g,
    const float* __restrict__ b, bf16* __restrict__ outb,
    const float* __restrict__ wa, long na, const float* __restrict__ wb, long nb,
    bf16* __restrict__ oa, bf16* __restrict__ ob2) {
    int bid = blockIdx.x;
    int tid = threadIdx.x;
    if (bid >= NTOK) {                   // cvt part
        long i = ((long)(bid - NTOK) * 256 + tid) * 4;
        const float* src; bf16* dst; long idx;
        if (i < na) { src = wa; dst = oa; idx = i; }
        else if (i < na + nb) { src = wb; dst = ob2; idx = i - na; }
        else return;
        float4 v = *(const float4*)(src + idx);
        *(uint2*)(dst + idx) = pack4bf(v.x, v.y, v.z, v.w);
        return;
    }
    // LN1, float4 path: 192 active lanes
    long base4 = (long)bid * 192;
    float4 v = {0.f, 0.f, 0.f, 0.f};
    if (tid < 192) v = ((const float4*)x)[base4 + tid];
    float s = v.x + v.y + v.z + v.w;
    __shared__ float red[4];
    #pragma unroll
    for (int o = 32; o; o >>= 1) s += __shfl_xor(s, o);
    if ((tid & 63) == 0) red[tid >> 6] = s;
    __syncthreads();
    s = red[0] + red[1] + red[2] + red[3];
    float mu = s * (1.f / DIM);
    float4 d = {v.x - mu, v.y - mu, v.z - mu, v.w - mu};
    float q = (tid < 192) ? (d.x*d.x + d.y*d.y + d.z*d.z + d.w*d.w) : 0.f;
    __shared__ float red2[4];
    #pragma unroll
    for (int o = 32; o; o >>= 1) q += __shfl_xor(q, o);
    if ((tid & 63) == 0) red2[tid >> 6] = q;
    __syncthreads();
    q = red2[0] + red2[1] + red2[2] + red2[3];
    float rstd = rsqrtf(q * (1.f / DIM) + 1e-5f);
    if (tid < 192) {
        float4 g4 = ((const float4*)g)[tid];
        float4 b4 = ((const float4*)b)[tid];
        ((uint2*)outb)[base4 + tid] = pack4bf(
            d.x * rstd * g4.x + b4.x, d.y * rstd * g4.y + b4.y,
            d.z * rstd * g4.z + b4.z, d.w * rstd * g4.w + b4.w);
    }
}

// ---------------- LN2 + x1 assembly + ROUTER, fully fused ----------------
// opart is f32: the router's top-2 selection is decision-sensitive, so the
// out-proj partials stay full precision (bf16 here flipped expert choices).
__global__ __launch_bounds__(256) void ln2x1r_kernel(
    const float* __restrict__ x, const float* __restrict__ out_b,
    const float* __restrict__ op, const float* __restrict__ g,
    const float* __restrict__ b, const float* __restrict__ rw,
    const float* __restrict__ rb, float* __restrict__ x1,
    bf16* __restrict__ t2b, int* __restrict__ e_sel,
    float* __restrict__ w_sel) {
    int t = blockIdx.x;
    int tid = threadIdx.x;
    const long TD4 = (long)NTOK * DIM / 4;
    long base4 = (long)t * 192;
    float4 v = {0.f, 0.f, 0.f, 0.f};
    if (tid < 192) {
        long i4 = base4 + tid;
        float4 xv = ((const float4*)x)[i4];
        float4 ob = ((const float4*)out_b)[tid];
        float4 o0 = ((const float4*)op)[i4];
        float4 o1 = ((const float4*)op)[i4 + TD4];
        v.x = xv.x + ob.x + o0.x + o1.x;
        v.y = xv.y + ob.y + o0.y + o1.y;
        v.z = xv.z + ob.z + o0.z + o1.z;
        v.w = xv.w + ob.w + o0.w + o1.w;
        ((float4*)x1)[i4] = v;
    }
    float s = v.x + v.y + v.z + v.w;
    __shared__ float red[4];
    #pragma unroll
    for (int o = 32; o; o >>= 1) s += __shfl_xor(s, o);
    if ((tid & 63) == 0) red[tid >> 6] = s;
    __syncthreads();
    s = red[0] + red[1] + red[2] + red[3];
    float mu = s * (1.f / DIM);
    float4 d = {v.x - mu, v.y - mu, v.z - mu, v.w - mu};
    float q = (tid < 192) ? (d.x*d.x + d.y*d.y + d.z*d.z + d.w*d.w) : 0.f;
    __shared__ float red2[4];
    #pragma unroll
    for (int o = 32; o; o >>= 1) q += __shfl_xor(q, o);
    if ((tid & 63) == 0) red2[tid >> 6] = q;
    __syncthreads();
    q = red2[0] + red2[1] + red2[2] + red2[3];
    float rstd = rsqrtf(q * (1.f / DIM) + 1e-5f);
    float4 ov = {0.f, 0.f, 0.f, 0.f};
    if (tid < 192) {
        float4 g4 = ((const float4*)g)[tid];
        float4 b4 = ((const float4*)b)[tid];
        ov.x = d.x * rstd * g4.x + b4.x;
        ov.y = d.y * rstd * g4.y + b4.y;
        ov.z = d.z * rstd * g4.z + b4.z;
        ov.w = d.w * rstd * g4.w + b4.w;
        ((uint2*)t2b)[base4 + tid] = pack4bf(ov.x, ov.y, ov.z, ov.w);
    }
    // Router: 8 logits via block-wide dot products with the in-register row.
    float part[NEXP];
    #pragma unroll
    for (int e = 0; e < NEXP; ++e) {
        float pv = 0.f;
        if (tid < 192) {
            float4 w4 = ((const float4*)rw)[(long)e * 192 + tid];
            pv = ov.x * w4.x + ov.y * w4.y + ov.z * w4.z + ov.w * w4.w;
        }
        part[e] = pv;
    }
    __shared__ float rred[4][NEXP];
    #pragma unroll
    for (int e = 0; e < NEXP; ++e) {
        float pv = part[e];
        #pragma unroll
        for (int o = 32; o; o >>= 1) pv += __shfl_xor(pv, o);
        if ((tid & 63) == 0) rred[tid >> 6][e] = pv;
    }
    __syncthreads();
    if (tid == 0) {
        float logits[NEXP];
        #pragma unroll
        for (int e = 0; e < NEXP; ++e)
            logits[e] = rred[0][e] + rred[1][e] + rred[2][e] + rred[3][e] + rb[e];
        int e0 = -1, e1 = -1;
        float l0 = -1e30f, l1 = -1e30f;
        #pragma unroll
        for (int e = 0; e < NEXP; ++e) {
            float l = logits[e];
            if (l > l0) { l1 = l0; e1 = e0; l0 = l; e0 = e; }
            else if (l > l1) { l1 = l; e1 = e; }
        }
        float p1 = expf(l1 - l0);
        float inv = 1.f / (1.f + p1);
        e_sel[t * 2] = e0;  e_sel[t * 2 + 1] = e1;
        w_sel[t * 2] = inv; w_sel[t * 2 + 1] = p1 * inv;
    }
}

// ---------------- MFMA GEMM device body (attention-side) ----------------
template<int WM, int WN, bool GROUPED, bool GELU, int OUTMODE>
__device__ __forceinline__ void dev_mfma_gemm(
    const bf16* __restrict__ A, const bf16* __restrict__ B,
    const float* __restrict__ bias, const float* __restrict__ resid,
    void* __restrict__ Cv,
    int M, int N, int K, int lda, int ldb, int ldc,
    int zdiv, int ksplit,
    long a_hi, long a_lo, long b_hi, long b_lo, long c_hi, long c_lo,
    long bias_stride, const int* __restrict__ grp_off, float alpha,
    int bx, int by, int bz, char* smem)
{
    constexpr int BM = 32 * WM, BN = 32 * WN;
    constexpr int ACH = BM * 4;     // 16B chunks in A tile
    constexpr int BCH = BN * 4;

    int z = bz;
    int ze = z / ksplit, ks = z % ksplit;
    int kper = K / ksplit;
    long aoff, boff, coff;
    int m_count = M;
    if (GROUPED) {
        int m0 = grp_off[ze], m1 = grp_off[ze + 1];
        m_count = m1 - m0;
        if (by * BM >= m_count) return;
        aoff = (long)m0 * lda;
        coff = (long)m0 * ldc;
        boff = (long)ze * b_hi;
    } else {
        int zh = ze / zdiv, zl = ze % zdiv;
        aoff = zh * a_hi + zl * a_lo;
        boff = zh * b_hi + zl * b_lo;
        coff = zh * c_hi + zl * c_lo;
    }
    const short* Ag = (const short*)(A + aoff);
    const short* Bg = (const short*)(B + boff);
    const float* biasp = bias ? bias + (long)ze * bias_stride : nullptr;
    float* Cf = (float*)Cv + coff;
    bf16*  Cb = (bf16*)Cv + coff;

    short* As = (short*)smem;
    short* Bs = As + BM * 32;

    int tid = threadIdx.x;
    int wv = tid >> 6, ln = tid & 63;
    int wr = wv >> 1, wc = wv & 1;
    int fr = ln & 15, fq = ln >> 4;
    int bm = by * BM, bn = bx * BN;

    f4v acc[WM][WN] = {};

    for (int k0 = ks * kper; k0 < (ks + 1) * kper; k0 += 32) {
        #pragma unroll
        for (int is = 0; is < ACH / 256; ++is) {
            int c = is * 256 + wv * 64 + ln;
            int m = c >> 2, kq = c & 3;
            int qg = kq ^ ((m >> 1) & 3);
            gload16(Ag + (long)(bm + m) * lda + k0 + qg * 8,
                    &As[(is * 256 + wv * 64) * 8]);
        }
        if constexpr (ACH % 256) {
            if (tid < ACH % 256) {
                int c = (ACH / 256) * 256 + tid;
                int m = c >> 2, kq = c & 3;
                int qg = kq ^ ((m >> 1) & 3);
                gload16(Ag + (long)(bm + m) * lda + k0 + qg * 8,
                        &As[((ACH / 256) * 256 + wv * 64) * 8]);
            }
        }
        #pragma unroll
        for (int is = 0; is < BCH / 256; ++is) {
            int c = is * 256 + wv * 64 + ln;
            int m = c >> 2, kq = c & 3;
            int qg = kq ^ ((m >> 1) & 3);
            gload16(Bg + (long)(bn + m) * ldb + k0 + qg * 8,
                    &Bs[(is * 256 + wv * 64) * 8]);
        }
        if constexpr (BCH % 256) {
            if (tid < BCH % 256) {
                int c = (BCH / 256) * 256 + tid;
                int m = c >> 2, kq = c & 3;
                int qg = kq ^ ((m >> 1) & 3);
                gload16(Bg + (long)(bn + m) * ldb + k0 + qg * 8,
                        &Bs[((BCH / 256) * 256 + wv * 64) * 8]);
            }
        }
        __syncthreads();
        s8v av[WM], bv[WN];
        #pragma unroll
        for (int i = 0; i < WM; ++i) {
            int row = wr * (WM * 16) + i * 16 + fr;
            av[i] = *(const s8v*)&As[row * 32 + (fq ^ ((row >> 1) & 3)) * 8];
        }
        #pragma unroll
        for (int j = 0; j < WN; ++j) {
            int row = wc * (WN * 16) + j * 16 + fr;
            bv[j] = *(const s8v*)&Bs[row * 32 + (fq ^ ((row >> 1) & 3)) * 8];
        }
        #pragma unroll
        for (int i = 0; i < WM; ++i)
            #pragma unroll
            for (int j = 0; j < WN; ++j)
                acc[i][j] = __builtin_amdgcn_mfma_f32_16x16x32_bf16(av[i], bv[j], acc[i][j], 0, 0, 0);
        __syncthreads();
    }

    #pragma unroll
    for (int i = 0; i < WM; ++i) {
        #pragma unroll
        for (int r = 0; r < 4; ++r) {
            int row = bm + wr * (WM * 16) + i * 16 + fq * 4 + r;
            if (GROUPED && row >= m_count) continue;
            #pragma unroll
            for (int j = 0; j < WN; ++j) {
                int col = bn + wc * (WN * 16) + j * 16 + fr;
                if (col < N) {
                    float v = acc[i][j][r] * alpha;
                    if (OUTMODE == 2) {
                        atomicAdd(&Cf[(long)row * ldc + col], v);
                    } else {
                        if (biasp) v += biasp[col];
                        if (GELU) v = 0.5f * v * (1.f + erff(v * 0.70710678118654752f));
                        if (resid) v += resid[(long)row * ldc + col];
                        if (OUTMODE == 1) Cb[(long)row * ldc + col] = __float2bfloat16(v);
                        else              Cf[(long)row * ldc + col] = v;
                    }
                }
            }
        }
    }
}

// Standalone wrapper (PV, out-proj)
template<int WM, int WN, bool GROUPED, bool GELU, int OUTMODE>
__global__ __launch_bounds__(256) void mfma_gemm(
    const bf16* A, const bf16* B, const float* bias, const float* resid,
    void* Cv, int M, int N, int K, int lda, int ldb, int ldc,
    int zdiv, int ksplit,
    long a_hi, long a_lo, long b_hi, long b_lo, long c_hi, long c_lo,
    long bias_stride, const int* grp_off, float alpha)
{
    __shared__ char smem[(32 * WM + 32 * WN) * 32 * 2];
    dev_mfma_gemm<WM, WN, GROUPED, GELU, OUTMODE>(
        A, B, bias, resid, Cv, M, N, K, lda, ldb, ldc, zdiv, ksplit,
        a_hi, a_lo, b_hi, b_lo, c_hi, c_lo, bias_stride, grp_off, alpha,
        blockIdx.x, blockIdx.y, blockIdx.z, smem);
}

// ---------------- weight transpose-convert tile (blocked output) -------------
__device__ __forceinline__ void dev_wtrans(int id,
                                           const float* __restrict__ w1,
                                           bf16* __restrict__ w1t,
                                           const float* __restrict__ w2,
                                           bf16* __restrict__ w2t,
                                           char* smem) {
    const float* in; bf16* out; int C, e, ct, rt;
    if (id < 4608) {                     // w1: 8 x (48 ct x 12 rt)
        e = id / 576; int rem = id % 576; ct = rem / 12; rt = rem % 12;
        in = w1; out = w1t; C = FFDIM;
    } else {
        id -= 4608;                      // w2: 8 x (12 ct x 48 rt)
        e = id / 576; int rem = id % 576; ct = rem / 48; rt = rem % 48;
        in = w2; out = w2t; C = DIM;
    }
    long ibase = (long)e * DIM * FFDIM;
    int rt0 = rt * 64, ct0 = ct * 64;
    float (*tile)[65] = (float(*)[65])smem;
    int t = threadIdx.x;
    {
        int q = t >> 4, cq = t & 15;
        #pragma unroll
        for (int i = 0; i < 4; ++i) {
            int row = q + i * 16;
            float4 v = *(const float4*)&in[ibase + (long)(rt0 + row) * C + ct0 + cq * 4];
            tile[row][cq * 4]     = v.x;
            tile[row][cq * 4 + 1] = v.y;
            tile[row][cq * 4 + 2] = v.z;
            tile[row][cq * 4 + 3] = v.w;
        }
    }
    __syncthreads();
    {
        int kb2 = t >> 6, n = t & 63;
        #pragma unroll
        for (int i = 0; i < 2; ++i) {
            int kblk = kb2 + 4 * i;
            unsigned w[4];
            #pragma unroll
            for (int j = 0; j < 4; ++j) {
                w[j] = ((unsigned)bf16bits(tile[kblk * 8 + 2 * j + 1][n]) << 16)
                     | bf16bits(tile[kblk * 8 + 2 * j][n]);
            }
            uint4 u; u.x = w[0]; u.y = w[1]; u.z = w[2]; u.w = w[3];
            *(uint4*)&out[ibase + ((long)(rt0 >> 3) + kblk) * C * 8 + (long)(ct0 + n) * 8] = u;
        }
    }
}

// ---------------- fused: qkv GEMM + w1 transpose (INTERLEAVED block map) ------
__global__ __launch_bounds__(256) void qkv_w1_kernel(
    const bf16* __restrict__ h_b, const bf16* __restrict__ in_wb,
    const float* __restrict__ in_b, bf16* __restrict__ qkv_b,
    const float* __restrict__ w1, bf16* __restrict__ w1t,
    const float* __restrict__ w2, bf16* __restrict__ w2t) {
    __shared__ char smem[16640];
    int bid = blockIdx.x;
    if (bid % 9 == 0) {
        int g = bid / 9;                               // 0..575
        dev_mfma_gemm<2, 2, false, false, 1>(
            h_b, in_wb, in_b, nullptr, qkv_b,
            NTOK, 3 * DIM, DIM, DIM, DIM, 3 * DIM,
            1, 1, 0, 0, 0, 0, 0, 0, 0, nullptr, 1.f,
            g % 36, g / 36, 0, smem);
    } else {
        int tr = bid - bid / 9 - 1;                    // 0..4607 = w1 ids
        dev_wtrans(tr, w1, w1t, w2, w2t, smem);
    }
}

// ---------------- fused: scores GEMM + w2 transpose (INTERLEAVED) -------------
__global__ __launch_bounds__(256) void scores_w2_kernel(
    const bf16* __restrict__ qkv_b, bf16* __restrict__ scores,
    const float* __restrict__ w1, bf16* __restrict__ w1t,
    const float* __restrict__ w2, bf16* __restrict__ w2t) {
    __shared__ char smem[16640];
    int bid = blockIdx.x;
    if (bid % 7 == 0) {
        int g = bid / 7;                               // 0..767
        dev_mfma_gemm<2, 4, false, false, 1>(
            qkv_b, qkv_b + DIM, nullptr, nullptr, scores,
            SEQ, SEQ, HDIM, 3 * DIM, 3 * DIM, SEQ,
            HEADS, 1, (long)SEQ * 3 * DIM, HDIM, (long)SEQ * 3 * DIM, HDIM,
            (long)HEADS * SEQ * SEQ, (long)SEQ * SEQ,
            0, nullptr, 0.125f,
            g % 4, (g >> 2) & 7, g >> 5, smem);
    } else {
        int tr = bid - bid / 7 - 1;                    // 0..4607 -> w2 ids
        dev_wtrans(4608 + tr, w1, w1t, w2, w2t, smem);
    }
}

// ---------------- MoE grouped GEMM v13: chunk-blocked B, bf16 partials -------
// OUTMODE: 0 = f32 store at ks*pstride; 1 = bf16 store (+bias,+GELU), KS==1;
//          3 = bf16 store at ks*pstride (split-K partials, no bias).
template<int FM, int FN, int XT, int YCAP, int KS, bool GELU, int OUTMODE, bool GATHER>
__global__ __launch_bounds__(256) void moe_gemm(
    const bf16* __restrict__ A, const bf16* __restrict__ B,
    const float* __restrict__ bias, void* __restrict__ Cv,
    int lda, int Nt, int ldc, int Ktot, long b_hi, long bias_stride,
    const int* __restrict__ grp_off, const int* __restrict__ entry_tok,
    int N, long pstride)
{
    static_assert(OUTMODE != 1 || KS == 1, "plain bf16 store requires no split-K");
    constexpr int BM = FM * 32, BN = FN * 32;
    constexpr int GA = BM / 64;
    constexpr int GB = BN / 64;
    constexpr int G = GA + GB;

    int bid = blockIdx.x;
    int e = bid & 7;
    int r = bid >> 3;
    int xt = r % XT; r /= XT;
    int yt = r % YCAP;
    int ks = r / YCAP;
    int m0 = grp_off[e], m1 = grp_off[e + 1];
    int m_count = m1 - m0;
    int bm = yt * BM;
    if (bm >= m_count) return;
    int bn = xt * BN;
    int kper = Ktot / KS;

    const short* Ag = (const short*)A + (GATHER ? 0 : (long)m0 * lda);
    const short* Bg = (const short*)(B + (long)e * b_hi);
    const float* biasp = bias ? bias + (long)e * bias_stride : nullptr;
    float* Cf = (float*)Cv + (long)m0 * ldc + (long)ks * pstride;
    bf16*  Cb = (bf16*)Cv + (long)m0 * ldc + (long)ks * pstride;

    __shared__ short As[3][BM * 32];
    __shared__ short Bs[3][BN * 32];

    int tid = threadIdx.x;
    int wv = tid >> 6, ln = tid & 63;
    int wr = wv >> 1, wc = wv & 1;
    int fr = ln & 15, fq = ln >> 4;

    long arow[GA];
    #pragma unroll
    for (int is = 0; is < GA; ++is) {
        int c = is * 256 + wv * 64 + ln;
        int m = c >> 2;
        if (GATHER) {
            int gi = m0 + bm + m;
            arow[is] = (long)entry_tok[gi < NENT ? gi : NENT - 1] * lda;
        } else {
            arow[is] = (long)(bm + m) * lda;
        }
    }

    f4v acc[FM][FN] = {};

    auto stage = [&](int buf, int k0) {
        #pragma unroll
        for (int is = 0; is < GA; ++is) {
            int c = is * 256 + wv * 64 + ln;
            int m = c >> 2, q = c & 3;
            int qg = q ^ ((m >> 1) & 3);
            gload16(Ag + arow[is] + k0 + qg * 8,
                    &As[buf][(is * 256 + wv * 64) * 8]);
        }
        #pragma unroll
        for (int is = 0; is < GB; ++is) {
            int c = is * 256 + wv * 64 + ln;
            int n = c >> 2, q = c & 3;
            int qg = q ^ ((n >> 1) & 3);
            gload16(Bg + ((long)(k0 >> 3) + qg) * Nt * 8 + (long)(bn + n) * 8,
                    &Bs[buf][(is * 256 + wv * 64) * 8]);
        }
    };

    int kbeg = ks * kper;
    int nit = kper / 32;
    stage(0, kbeg);
    if (nit > 1) stage(1, kbeg + 32);

    for (int it = 0; it < nit; ++it) {
        if (it + 1 < nit) asm volatile("s_waitcnt vmcnt(%0)" :: "i"(G) : "memory");
        else              asm volatile("s_waitcnt vmcnt(0)" ::: "memory");
        __builtin_amdgcn_s_barrier();
        if (it + 2 < nit) stage((it + 2) % 3, kbeg + (it + 2) * 32);
        int cur = it % 3;
        __builtin_amdgcn_s_setprio(1);
        {
            s8v av[FM], bv[FN];
            #pragma unroll
            for (int i = 0; i < FM; ++i) {
                int row = wr * (FM * 16) + i * 16 + fr;
                av[i] = *(const s8v*)&As[cur][row * 32 + (fq ^ ((row >> 1) & 3)) * 8];
            }
            #pragma unroll
            for (int j = 0; j < FN; ++j) {
                int row = wc * (FN * 16) + j * 16 + fr;
                bv[j] = *(const s8v*)&Bs[cur][row * 32 + (fq ^ ((row >> 1) & 3)) * 8];
            }
            #pragma unroll
            for (int i = 0; i < FM; ++i)
                #pragma unroll
                for (int j = 0; j < FN; ++j)
                    acc[i][j] = __builtin_amdgcn_mfma_f32_16x16x32_bf16(av[i], bv[j], acc[i][j], 0, 0, 0);
        }
        __builtin_amdgcn_s_setprio(0);
    }

    #pragma unroll
    for (int i = 0; i < FM; ++i) {
        #pragma unroll
        for (int rr = 0; rr < 4; ++rr) {
            int row = bm + wr * (FM * 16) + i * 16 + fq * 4 + rr;
            if (row >= m_count) continue;
            #pragma unroll
            for (int j = 0; j < FN; ++j) {
                int col = bn + wc * (FN * 16) + j * 16 + fr;
                float v = acc[i][j][rr];
                if (OUTMODE == 0) {
                    Cf[(long)row * ldc + col] = v;
                } else if (OUTMODE == 3) {
                    Cb[(long)row * ldc + col] = __float2bfloat16(v);
                } else {
                    if (biasp) v += biasp[col];
                    if (GELU) v = 0.5f * v * (1.f + erff(v * 0.70710678118654752f));
                    Cb[(long)row * ldc + col] = __float2bfloat16(v);
                }
            }
        }
    }
}

// ---------------- fused: softmax (3072 blocks) + V transpose (192 blocks) ----
__global__ __launch_bounds__(256) void softmax_vt_kernel(
    const bf16* __restrict__ s, bf16* __restrict__ attn,
    const bf16* __restrict__ qkvb, bf16* __restrict__ vt) {
    __shared__ short tile[64][65];
    int bid = blockIdx.x;
    int t = threadIdx.x;
    if (bid < 3072) {                    // softmax: wave per row
        long row = (long)bid * 4 + (t >> 6);
        int ln = t & 63;
        const unsigned* p = (const unsigned*)(s + row * 512);
        uint4 v = *(const uint4*)(p + ln * 4);
        unsigned u[4] = {v.x, v.y, v.z, v.w};
        float f[8];
        #pragma unroll
        for (int j = 0; j < 4; ++j) {
            f[2*j]   = bfbits2f(u[j] << 16);
            f[2*j+1] = bfbits2f(u[j] & 0xffff0000u);
        }
        float m = f[0];
        #pragma unroll
        for (int j = 1; j < 8; ++j) m = fmaxf(m, f[j]);
        #pragma unroll
        for (int o = 32; o; o >>= 1) m = fmaxf(m, __shfl_xor(m, o));
        float e[8], ssum = 0.f;
        #pragma unroll
        for (int j = 0; j < 8; ++j) { e[j] = expf(f[j] - m); ssum += e[j]; }
        #pragma unroll
        for (int o = 32; o; o >>= 1) ssum += __shfl_xor(ssum, o);
        float inv = 1.f / ssum;
        unsigned w[4];
        #pragma unroll
        for (int j = 0; j < 4; ++j) {
            bf16 lo = __float2bfloat16(e[2*j] * inv);
            bf16 hi = __float2bfloat16(e[2*j+1] * inv);
            w[j] = ((unsigned)*(unsigned short*)&hi << 16) | *(unsigned short*)&lo;
        }
        uint4 o4; o4.x = w[0]; o4.y = w[1]; o4.z = w[2]; o4.w = w[3];
        *(uint4*)((unsigned*)(attn + row * 512) + ln * 4) = o4;
    } else {                             // V transpose
        int id = bid - 3072;             // 0..191
        int st = id % 8;
        int z = id / 8;
        int b = z / HEADS, h = z % HEADS;
        int d = t & 63, s0 = t >> 6;
        const short* q = (const short*)qkvb;
        #pragma unroll
        for (int i = 0; i < 16; ++i) {
            int sq = st * 64 + s0 + i * 4;
            tile[s0 + i * 4][d] = q[(long)(b * SEQ + sq) * 2304 + 2 * DIM + h * HDIM + d];
        }
        __syncthreads();
        short* o = (short*)vt;
        #pragma unroll
        for (int i = 0; i < 16; ++i) {
            int d2 = (t >> 6) + i * 4;
            o[(long)(z * 64 + d2) * 512 + st * 64 + (t & 63)] = tile[t & 63][d2];
        }
    }
}

// ---------------- build per-expert entry lists (single block) ----------------
__global__ __launch_bounds__(1024) void build_lists(const int* __restrict__ e_sel,
                                                    int* __restrict__ entry_tok,
                                                    int* __restrict__ pos,
                                                    int* __restrict__ grp_off) {
    __shared__ int cnt[NEXP];
    __shared__ int off[NEXP + 1];
    __shared__ int cur[NEXP];
    int tid = threadIdx.x;
    if (tid < NEXP) cnt[tid] = 0;
    __syncthreads();
    for (int i = tid; i < NENT; i += 1024) atomicAdd(&cnt[e_sel[i]], 1);
    __syncthreads();
    if (tid == 0) {
        off[0] = 0;
        for (int e = 0; e < NEXP; ++e) off[e + 1] = off[e] + cnt[e];
        for (int e = 0; e < NEXP; ++e) cur[e] = off[e];
    }
    __syncthreads();
    for (int i = tid; i < NENT; i += 1024) {
        int e = e_sel[i];
        int p = atomicAdd(&cur[e], 1);
        entry_tok[p] = i >> 1;
        pos[i] = p;
    }
    if (tid < NEXP + 1) grp_off[tid] = off[tid];
}

// ---------------- final combine (float4 out, bf16 partials) ------------------
// out = x1 + sum_s w_s*(b2[e_s] + sum_ks ypart_bf16)
__global__ __launch_bounds__(256) void combine_kernel(const float* __restrict__ x1,
                                                      const bf16* __restrict__ ypart,
                                                      const float* __restrict__ b2,
                                                      const int* __restrict__ pos,
                                                      const int* __restrict__ e_sel,
                                                      const float* __restrict__ wsel,
                                                      float* __restrict__ out) {
    long i4 = (long)blockIdx.x * 256 + threadIdx.x;      // 4-elem units; 196608 total
    if (i4 >= (long)NTOK * DIM / 4) return;
    int t = (int)(i4 / 192), d4 = (int)(i4 % 192);
    const float4* x1v = (const float4*)x1;
    const uint2* ypv = (const uint2*)ypart;              // 4 bf16 per uint2
    const float4* b2v = (const float4*)b2;
    float4 v = x1v[i4];
    #pragma unroll
    for (int s = 0; s < 2; ++s) {
        long base = (long)pos[t * 2 + s] * 192 + d4;
        float4 y = b2v[(long)e_sel[t * 2 + s] * 192 + d4];
        #pragma unroll
        for (int ks = 0; ks < 4; ++ks) {
            uint2 pp = ypv[base + ks * (YPS / 4)];
            y.x += bfbits2f(pp.x << 16);
            y.y += bfbits2f(pp.x & 0xffff0000u);
            y.z += bfbits2f(pp.y << 16);
            y.w += bfbits2f(pp.y & 0xffff0000u);
        }
        float w = wsel[t * 2 + s];
        v.x += w * y.x; v.y += w * y.y; v.z += w * y.z; v.w += w * y.w;
    }
    ((float4*)out)[i4] = v;
}

extern "C" void kernel_launch(void* const* d_in, const int* in_sizes, int n_in,
                              void* d_out, int out_size, void* d_ws, size_t ws_size,
                              hipStream_t stream) {
    const float* x        = (const float*)d_in[0];
    const float* ln1_g    = (const float*)d_in[1];
    const float* ln1_b    = (const float*)d_in[2];
    const float* ln2_g    = (const float*)d_in[3];
    const float* ln2_b    = (const float*)d_in[4];
    const float* in_w     = (const float*)d_in[5];
    const float* in_b     = (const float*)d_in[6];
    const float* out_w    = (const float*)d_in[7];
    const float* out_b    = (const float*)d_in[8];
    const float* router_w = (const float*)d_in[9];
    const float* router_b = (const float*)d_in[10];
    const float* w1       = (const float*)d_in[11];
    const float* b1       = (const float*)d_in[12];
    const float* w2       = (const float*)d_in[13];
    const float* b2       = (const float*)d_in[14];
    float* out = (float*)d_out;

    const long TD = (long)NTOK * DIM;
    char* p = (char*)d_ws;
    size_t off = 0;
    auto alloc = [&](size_t bytes) -> void* {
        void* r = p + off; off += (bytes + 255) & ~(size_t)255; return r;
    };
    bf16*  h_b    = (bf16*)alloc(TD * 2);
    bf16*  in_wb  = (bf16*)alloc(2304L * 768 * 2);
    bf16*  qkv_b  = (bf16*)alloc(1024L * 2304 * 2);
    bf16*  out_wb = (bf16*)alloc(768L * 768 * 2);
    bf16*  vt_b   = (bf16*)alloc((24L * 64 + 64) * 512 * 2);
    bf16*  oat_b  = (bf16*)alloc(TD * 2);
    float* opart  = (float*)alloc(2 * TD * 4);                 // out-proj f32 K-partials
    float* x1     = (float*)alloc(TD * 4);
    bf16*  t2b    = (bf16*)alloc((NTOK + 256L) * DIM * 2);     // +pad (BM overread)
    bf16*  w1t    = (bf16*)alloc(8L * 3072 * 768 * 2);
    bf16*  w2t    = (bf16*)alloc(8L * 768 * 3072 * 2);
    bf16*  scores = (bf16*)alloc(24L * 512 * 512 * 2);
    bf16*  attn   = (bf16*)alloc(24L * 512 * 512 * 2);
    bf16*  hid    = (bf16*)alloc((2048L + 256) * 3072 * 2);    // +pad
    bf16*  ypart  = (bf16*)alloc(4 * YPS * 2);                 // 4 split-K bf16 partials
    int*   e_sel     = (int*)alloc(NENT * 4);
    float* w_sel     = (float*)alloc(NENT * 4);
    int*   entry_tok = (int*)alloc(NENT * 4);
    int*   pos       = (int*)alloc(NENT * 4);
    int*   grp_off   = (int*)alloc(64);

    // 1. FUSED: LN1 (1024 blocks, float4) + attention weight cvt (2304 blocks)
    ln1_cvt_kernel<<<NTOK + 2304, 256, 0, stream>>>(
        x, ln1_g, ln1_b, h_b,
        in_w, 2304L * 768, out_w, 768L * 768, in_wb, out_wb);
    // 2. FUSED+INTERLEAVED: qkv GEMM (576) + w1 transpose (4608)
    qkv_w1_kernel<<<576 + 4608, 256, 0, stream>>>(h_b, in_wb, in_b, qkv_b,
                                                  w1, w1t, w2, w2t);
    // 3. FUSED+INTERLEAVED: scores GEMM (768) + w2 transpose (4608)
    scores_w2_kernel<<<768 + 4608, 256, 0, stream>>>(qkv_b, scores,
                                                     w1, w1t, w2, w2t);
    // 4. FUSED: softmax (3072) + V transpose (192)
    softmax_vt_kernel<<<3072 + 192, 256, 0, stream>>>(scores, attn, qkv_b, vt_b);
    // 5. o = attn @ V -> oat bf16   BM=32: 384 blocks
    mfma_gemm<1, 2, false, false, 1><<<dim3(1, 16, 24), 256, 0, stream>>>(
        attn, vt_b, nullptr, nullptr, oat_b,
        SEQ, HDIM, SEQ, SEQ, SEQ, DIM,
        HEADS, 1, (long)HEADS * SEQ * SEQ, (long)SEQ * SEQ,
        (long)HEADS * HDIM * SEQ, (long)HDIM * SEQ,
        (long)SEQ * DIM, HDIM,
        0, nullptr, 1.f);
    // 6. out-proj split-K x2, f32 partial stores (router-decision-safe)
    mfma_gemm<2, 2, false, false, 0><<<dim3(12, 16, 2), 256, 0, stream>>>(
        oat_b, out_wb, nullptr, nullptr, opart,
        NTOK, DIM, 384, DIM, DIM, DIM,
        2, 1, 0, 384, 0, 384, 0, TD, 0, nullptr, 1.f);
    // 7. FUSED: LN2 + x1 assembly + router (float4)
    ln2x1r_kernel<<<NTOK, 256, 0, stream>>>(x, out_b, opart, ln2_g, ln2_b,
                                            router_w, router_b,
                                            x1, t2b, e_sel, w_sel);
    // 8. build lists
    build_lists<<<1, 1024, 0, stream>>>(e_sel, entry_tok, pos, grp_off);
    // 9. FFN1 grouped, GATHER-fused A: hid = gelu(t2b[tok] @ w1 + b1) -> bf16
    moe_gemm<4, 4, 24, 8, 1, true, 1, true><<<8 * 24 * 8, 256, 0, stream>>>(
        t2b, w1t, b1, hid,
        DIM, FFDIM, FFDIM, DIM, (long)FFDIM * DIM, FFDIM, grp_off, entry_tok,
        FFDIM, 0);
    // 10. FFN2 grouped split-K x4, bf16 partial stores (routing-downstream, safe)
    moe_gemm<4, 4, 6, 8, 4, false, 3, false><<<8 * 6 * 8 * 4, 256, 0, stream>>>(
        hid, w2t, nullptr, ypart,
        FFDIM, DIM, DIM, FFDIM, (long)FFDIM * DIM, 0, grp_off, nullptr,
        DIM, YPS);
    // 11. combine (float4 out, bf16 partials)
    combine_kernel<<<768, 256, 0, stream>>>(x1, ypart, b2, pos, e_sel, w_sel, out);
}